// Round 1
// baseline (2150.462 us; speedup 1.0000x reference)
//
#include <hip/hip_runtime.h>
#include <math.h>

typedef __attribute__((ext_vector_type(8))) __bf16 bf16x8;
typedef __attribute__((ext_vector_type(8))) unsigned short u16x8;
typedef __attribute__((ext_vector_type(4))) float f32x4;

// ---------- helpers ----------
__device__ __forceinline__ float bf2f(unsigned short h){
  return __uint_as_float(((unsigned int)h) << 16);
}
__device__ __forceinline__ unsigned short f2bf(float f){
  unsigned int u = __float_as_uint(f);
  unsigned int r = (u + 0x7FFFu + ((u >> 16) & 1u)) >> 16;  // RNE
  return (unsigned short)r;
}

// ---------- init / scatter ----------
__global__ void init_misc(int* slot, float* acc){
  int i = blockIdx.x * 256 + threadIdx.x;
  if (i < 64*196) slot[i] = -1;
  if (i == 64*196) acc[0] = 0.0f;
}

__global__ void scatter_slots(const int* __restrict__ shuf, int* __restrict__ slot){
  int i = blockIdx.x * 256 + threadIdx.x;
  if (i >= 64*147) return;
  int b = i / 147, j = i % 147;
  slot[b*196 + shuf[b*196 + j]] = j;
}

__global__ void conv_bf16(const float* __restrict__ src, unsigned short* __restrict__ dst, int n){
  int i = blockIdx.x * 256 + threadIdx.x;
  if (i < n) dst[i] = f2bf(src[i]);
}

// ---------- patchify + gather into padded bf16 A-matrices ----------
// mask rows: (b, i<160) padded from 147; unmask rows: (b, u<64) padded from 49
__global__ __launch_bounds__(256) void patchify(const float* __restrict__ x, const int* __restrict__ shuf,
                         unsigned short* __restrict__ maskA, unsigned short* __restrict__ unmaskA,
                         int* __restrict__ tokm, int* __restrict__ toku)
{
  const int blk = blockIdx.x;
  const int b = blk / 224, ip = blk % 224;
  unsigned short* dst;
  int p = 0, valid;
  if (ip < 160){
    valid = (ip < 147);
    if (valid) p = shuf[b*196 + ip];
    dst = maskA + (size_t)(b*160 + ip) * 768;
    if (threadIdx.x == 0) tokm[b*160 + ip] = p;
  } else {
    const int u = ip - 160;
    valid = (u < 49);
    if (valid) p = shuf[b*196 + 147 + u];
    dst = unmaskA + (size_t)(b*64 + u) * 768;
    if (threadIdx.x == 0) toku[b*64 + u] = p;
  }
  const int gh = p / 14, gw = p % 14;
  const float* xb = x + (size_t)b * 3*224*224;
  for (int d = threadIdx.x; d < 768; d += 256){
    float v = 0.0f;
    if (valid){
      const int c = d % 3, pwi = (d/3) & 15, phi = d / 48;
      v = xb[(size_t)c*224*224 + (size_t)(gh*16+phi)*224 + (gw*16+pwi)];
    }
    dst[d] = f2bf(v);
  }
}

// ---------- bf16 MFMA GEMM: C[M,N] = A[M,K] @ W[N,K]^T + bias (+epilogue) ----------
// MODE 0: bias -> bf16 out.  MODE 1: bias + pos_embed[tok[row]] -> bf16.
// MODE 2: bias + gelu(tanh approx) -> bf16.  MODE 3: bias -> f32 out.
// 128x128 tile, 4 waves (2x2 of 64x64), BK=32, mfma_f32_16x16x32_bf16.
template<int MODE>
__global__ __launch_bounds__(256) void gemm_k(
    const unsigned short* __restrict__ A, const unsigned short* __restrict__ W,
    const float* __restrict__ bias, const float* __restrict__ pe,
    const int* __restrict__ tok, unsigned short* __restrict__ outb,
    float* __restrict__ outf, int M, int N, int K)
{
  __shared__ unsigned short As[128*40];  // +8 pad keeps 16B align, breaks bank stride
  __shared__ unsigned short Bs[128*40];
  const int t = threadIdx.x;
  const int tn = blockIdx.x * 128;
  const int tm = blockIdx.y * 128;
  const int wave = t >> 6, lane = t & 63;
  const int wr = (wave >> 1) * 64, wc = (wave & 1) * 64;
  const int lr = lane & 15, lg = lane >> 4;

  f32x4 acc[4][4] = {};

  const int r0 = t >> 2;          // row 0..63 (chunk 0) / +64 (chunk 1)
  const int c0 = (t & 3) * 8;     // k-offset within BK=32

  for (int k0 = 0; k0 < K; k0 += 32){
    u16x8 ra0 = *(const u16x8*)(A + (size_t)(tm + r0) * K + k0 + c0);
    u16x8 ra1 = *(const u16x8*)(A + (size_t)(tm + 64 + r0) * K + k0 + c0);
    u16x8 rb0 = *(const u16x8*)(W + (size_t)(tn + r0) * K + k0 + c0);
    u16x8 rb1 = *(const u16x8*)(W + (size_t)(tn + 64 + r0) * K + k0 + c0);
    __syncthreads();
    *(u16x8*)&As[r0 * 40 + c0] = ra0;
    *(u16x8*)&As[(64 + r0) * 40 + c0] = ra1;
    *(u16x8*)&Bs[r0 * 40 + c0] = rb0;
    *(u16x8*)&Bs[(64 + r0) * 40 + c0] = rb1;
    __syncthreads();
    bf16x8 av[4], bv[4];
    #pragma unroll
    for (int mi = 0; mi < 4; mi++) av[mi] = *(const bf16x8*)&As[(wr + mi*16 + lr)*40 + lg*8];
    #pragma unroll
    for (int ni = 0; ni < 4; ni++) bv[ni] = *(const bf16x8*)&Bs[(wc + ni*16 + lr)*40 + lg*8];
    #pragma unroll
    for (int mi = 0; mi < 4; mi++)
      #pragma unroll
      for (int ni = 0; ni < 4; ni++)
        acc[mi][ni] = __builtin_amdgcn_mfma_f32_16x16x32_bf16(av[mi], bv[ni], acc[mi][ni], 0, 0, 0);
  }

  // epilogue: C/D layout col=lane&15, row=(lane>>4)*4+jj  [m89/m91-verified]
  #pragma unroll
  for (int ni = 0; ni < 4; ni++){
    const int gcol = tn + wc + ni*16 + lr;
    const float bval = bias[gcol];
    #pragma unroll
    for (int mi = 0; mi < 4; mi++){
      #pragma unroll
      for (int jj = 0; jj < 4; jj++){
        const int grow = tm + wr + mi*16 + lg*4 + jj;
        float v = acc[mi][ni][jj] + bval;
        if constexpr (MODE == 1) v += pe[(size_t)tok[grow] * 512 + gcol];
        if constexpr (MODE == 2){
          const float u = v;
          v = 0.5f * u * (1.0f + tanhf(0.7978845608f * (u + 0.044715f * u * u * u)));
        }
        if constexpr (MODE == 3) outf[(size_t)grow * N + gcol] = v;
        else                     outb[(size_t)grow * N + gcol] = f2bf(v);
      }
    }
  }
}

// ---------- attention: block per (b,h); q 147x64, k/v 49x64 ----------
__global__ __launch_bounds__(256) void attn_k(const unsigned short* __restrict__ qb,
                                              const unsigned short* __restrict__ kv,
                                              unsigned short* __restrict__ attnout)
{
  const int b = blockIdx.x >> 3, h = blockIdx.x & 7;
  __shared__ float ks[49][64];
  __shared__ float vs[49][64];
  __shared__ float pwt[147][49];
  __shared__ float inv_[147];
  const int t = threadIdx.x;
  for (int idx = t; idx < 49*64; idx += 256){
    const int j = idx >> 6, d = idx & 63;
    const size_t base = (size_t)(b*64 + j)*1024 + h*64 + d;
    ks[j][d] = bf2f(kv[base]);
    vs[j][d] = bf2f(kv[base + 512]);
  }
  __syncthreads();
  if (t < 147){
    float qv[64];
    const unsigned short* qp = qb + (size_t)(b*160 + t)*512 + h*64;
    #pragma unroll
    for (int d = 0; d < 64; d++) qv[d] = bf2f(qp[d]);
    for (int j = 0; j < 49; j++){
      float s = 0.0f;
      #pragma unroll
      for (int d = 0; d < 64; d++) s += qv[d] * ks[j][d];
      pwt[t][j] = s * 0.125f;   // 1/sqrt(64)
    }
    float m = -1e30f;
    for (int j = 0; j < 49; j++) m = fmaxf(m, pwt[t][j]);
    float sum = 0.0f;
    for (int j = 0; j < 49; j++){ const float e = __expf(pwt[t][j] - m); pwt[t][j] = e; sum += e; }
    inv_[t] = 1.0f / sum;
  }
  __syncthreads();
  for (int idx = t; idx < 147*64; idx += 256){
    const int i = idx >> 6, d = idx & 63;
    float s = 0.0f;
    for (int j = 0; j < 49; j++) s += pwt[i][j] * vs[j][d];
    s *= inv_[i];
    attnout[(size_t)(b*160 + i)*512 + h*64 + d] = f2bf(s);
  }
}

// ---------- final: three images + |err| accumulation in one pass over x ----------
__global__ __launch_bounds__(256) void finalize_k(const float* __restrict__ x, const int* __restrict__ slot,
                           const float* __restrict__ pred, const float* __restrict__ noise,
                           float* __restrict__ out, float* __restrict__ acc)
{
  const int idx = blockIdx.x * 256 + threadIdx.x;   // < 9,633,792
  const int w = idx % 224;
  const int h = (idx / 224) % 224;
  const int c = (idx / (224*224)) % 3;
  const int b = idx / (224*224*3);
  const float xv = x[idx];
  const int p = (h >> 4) * 14 + (w >> 4);
  const int s = slot[b*196 + p];
  float rec = xv, noi = xv, mim = xv, a = 0.0f;
  if (s >= 0){
    const int d = (h & 15)*48 + (w & 15)*3 + c;
    rec = pred[(size_t)(b*160 + s)*768 + d];
    noi = noise[(size_t)(b*147 + s)*768 + d];
    mim = 1.0f;
    a = fabsf(rec - xv);
  }
  out[idx] = rec;
  out[9633792 + idx] = noi;
  out[19267585 + idx] = mim;
  #pragma unroll
  for (int o = 32; o > 0; o >>= 1) a += __shfl_down(a, o);
  if ((threadIdx.x & 63) == 0) atomicAdd(acc, a);
}

__global__ void mse_write(const float* __restrict__ acc, float* __restrict__ out){
  out[19267584] = acc[0] * (1.0f / 7225344.0f);   // / (64*147*768)
}

// ---------- launch ----------
extern "C" void kernel_launch(void* const* d_in, const int* in_sizes, int n_in,
                              void* d_out, int out_size, void* d_ws, size_t ws_size,
                              hipStream_t stream)
{
  const float* x     = (const float*)d_in[0];
  const int*   shuf  = (const int*)d_in[1];
  const float* W_pe  = (const float*)d_in[2];
  const float* b_pe  = (const float*)d_in[3];
  const float* pos   = (const float*)d_in[4];
  const float* encW  = (const float*)d_in[5];
  const float* encB  = (const float*)d_in[6];
  const float* inW   = (const float*)d_in[7];
  const float* inB   = (const float*)d_in[8];
  const float* outW  = (const float*)d_in[9];
  const float* outB  = (const float*)d_in[10];
  const float* headW = (const float*)d_in[11];
  const float* headB = (const float*)d_in[12];
  const float* noise = (const float*)d_in[13];
  float* out = (float*)d_out;

  char* ws = (char*)d_ws;
  size_t cur = 0;
  auto alloc = [&](size_t bytes){ size_t o = cur; cur += (bytes + 255) & ~(size_t)255; return o; };

  int*   slot  = (int*)(ws + alloc(64*196*4));
  int*   tokm  = (int*)(ws + alloc(10240*4));
  int*   toku  = (int*)(ws + alloc(4096*4));
  float* acc   = (float*)(ws + alloc(256));
  unsigned short* wpe_b   = (unsigned short*)(ws + alloc((size_t)393216*2));
  unsigned short* encw_b  = (unsigned short*)(ws + alloc((size_t)262144*2));
  unsigned short* inw_b   = (unsigned short*)(ws + alloc((size_t)786432*2));
  unsigned short* outw_b  = (unsigned short*)(ws + alloc((size_t)262144*2));
  unsigned short* headw_b = (unsigned short*)(ws + alloc((size_t)393216*2));
  // R0: maskA(15728640B) | unmaskA(6291456B) | masktok(10485760B); later attnout, then pred alias it
  char* R0 = ws + alloc(32505856);
  unsigned short* maskA   = (unsigned short*)R0;
  unsigned short* unmaskA = (unsigned short*)(R0 + 15728640);
  unsigned short* masktok = (unsigned short*)(R0 + 22020096);
  unsigned short* attnout = (unsigned short*)R0;   // alive attention..GEMM6; maskA/unmaskA/masktok dead by then
  float*          pred    = (float*)R0;            // alive GEMM7..finalize; attnout dead by then
  unsigned short* umtok = (unsigned short*)(ws + alloc((size_t)2097152*2));
  unsigned short* enc   = (unsigned short*)(ws + alloc((size_t)2097152*2));
  unsigned short* qb    = (unsigned short*)(ws + alloc((size_t)5242880*2));
  unsigned short* kvb   = (unsigned short*)(ws + alloc((size_t)4194304*2));
  unsigned short* proj  = (unsigned short*)(ws + alloc((size_t)5242880*2));

  init_misc<<<50, 256, 0, stream>>>(slot, acc);
  scatter_slots<<<(64*147 + 255)/256, 256, 0, stream>>>(shuf, slot);
  conv_bf16<<<393216/256, 256, 0, stream>>>(W_pe, wpe_b, 393216);
  conv_bf16<<<262144/256, 256, 0, stream>>>(encW, encw_b, 262144);
  conv_bf16<<<786432/256, 256, 0, stream>>>(inW, inw_b, 786432);
  conv_bf16<<<262144/256, 256, 0, stream>>>(outW, outw_b, 262144);
  conv_bf16<<<393216/256, 256, 0, stream>>>(headW, headw_b, 393216);
  patchify<<<64*224, 256, 0, stream>>>(x, shuf, maskA, unmaskA, tokm, toku);

  // unmask_tokens = unmaskA @ W_pe^T + b_pe + pe[tok]
  gemm_k<1><<<dim3(4,32), 256, 0, stream>>>(unmaskA, wpe_b, b_pe, pos, toku, umtok, nullptr, 4096, 512, 768);
  // encoded = gelu(unmask_tokens @ enc_W^T + enc_b)
  gemm_k<2><<<dim3(4,32), 256, 0, stream>>>(umtok, encw_b, encB, nullptr, nullptr, enc, nullptr, 4096, 512, 512);
  // mask_tokens = maskA @ W_pe^T + b_pe + pe[tok]
  gemm_k<1><<<dim3(4,80), 256, 0, stream>>>(maskA, wpe_b, b_pe, pos, tokm, masktok, nullptr, 10240, 512, 768);
  // q = mask_tokens @ Wq^T + bq
  gemm_k<0><<<dim3(4,80), 256, 0, stream>>>(masktok, inw_b, inB, nullptr, nullptr, qb, nullptr, 10240, 512, 512);
  // kv = encoded @ [Wk;Wv]^T + [bk;bv]
  gemm_k<0><<<dim3(8,32), 256, 0, stream>>>(enc, inw_b + (size_t)512*512, inB + 512, nullptr, nullptr, kvb, nullptr, 4096, 1024, 512);
  attn_k<<<512, 256, 0, stream>>>(qb, kvb, attnout);
  // proj = attn_out @ out_w^T + out_b
  gemm_k<0><<<dim3(4,80), 256, 0, stream>>>(attnout, outw_b, outB, nullptr, nullptr, proj, nullptr, 10240, 512, 512);
  // pred = proj @ head_W^T + head_b  (f32 out)
  gemm_k<3><<<dim3(6,80), 256, 0, stream>>>(proj, headw_b, headB, nullptr, nullptr, nullptr, pred, 10240, 768, 512);

  finalize_k<<<37632, 256, 0, stream>>>(x, slot, pred, noise, out, acc);
  mse_write<<<1, 1, 0, stream>>>(acc, out);
}

// Round 2
// 307.830 us; speedup vs baseline: 6.9859x; 6.9859x over previous
//
#include <hip/hip_runtime.h>
#include <math.h>

typedef __attribute__((ext_vector_type(8))) __bf16 bf16x8;
typedef __attribute__((ext_vector_type(8))) unsigned short u16x8;
typedef __attribute__((ext_vector_type(4))) float f32x4;

// ---------- helpers ----------
__device__ __forceinline__ float bf2f(unsigned short h){
  return __uint_as_float(((unsigned int)h) << 16);
}
__device__ __forceinline__ unsigned short f2bf(float f){
  unsigned int u = __float_as_uint(f);
  unsigned int r = (u + 0x7FFFu + ((u >> 16) & 1u)) >> 16;  // RNE
  return (unsigned short)r;
}

// ---------- init / scatter ----------
__global__ void init_misc(int* slot){
  int i = blockIdx.x * 256 + threadIdx.x;
  if (i < 64*196) slot[i] = -1;
}

__global__ void scatter_slots(const int* __restrict__ shuf, int* __restrict__ slot){
  int i = blockIdx.x * 256 + threadIdx.x;
  if (i >= 64*147) return;
  int b = i / 147, j = i % 147;
  slot[b*196 + shuf[b*196 + j]] = j;
}

__global__ void conv_bf16(const float* __restrict__ src, unsigned short* __restrict__ dst, int n){
  int i = blockIdx.x * 256 + threadIdx.x;
  if (i < n) dst[i] = f2bf(src[i]);
}

// ---------- patchify + gather into padded bf16 A-matrices ----------
// mask rows: (b, i<160) padded from 147; unmask rows: (b, u<64) padded from 49
__global__ __launch_bounds__(256) void patchify(const float* __restrict__ x, const int* __restrict__ shuf,
                         unsigned short* __restrict__ maskA, unsigned short* __restrict__ unmaskA,
                         int* __restrict__ tokm, int* __restrict__ toku)
{
  const int blk = blockIdx.x;
  const int b = blk / 224, ip = blk % 224;
  unsigned short* dst;
  int p = 0, valid;
  if (ip < 160){
    valid = (ip < 147);
    if (valid) p = shuf[b*196 + ip];
    dst = maskA + (size_t)(b*160 + ip) * 768;
    if (threadIdx.x == 0) tokm[b*160 + ip] = p;
  } else {
    const int u = ip - 160;
    valid = (u < 49);
    if (valid) p = shuf[b*196 + 147 + u];
    dst = unmaskA + (size_t)(b*64 + u) * 768;
    if (threadIdx.x == 0) toku[b*64 + u] = p;
  }
  const int gh = p / 14, gw = p % 14;
  const float* xb = x + (size_t)b * 3*224*224;
  for (int d = threadIdx.x; d < 768; d += 256){
    float v = 0.0f;
    if (valid){
      const int c = d % 3, pwi = (d/3) & 15, phi = d / 48;
      v = xb[(size_t)c*224*224 + (size_t)(gh*16+phi)*224 + (gw*16+pwi)];
    }
    dst[d] = f2bf(v);
  }
}

// ---------- bf16 MFMA GEMM: C[M,N] = A[M,K] @ W[N,K]^T + bias (+epilogue) ----------
// MODE 0: bias -> bf16 out.  MODE 1: bias + pos_embed[tok[row]] -> bf16.
// MODE 2: bias + gelu(tanh approx) -> bf16.  MODE 3: bias -> f32 out.
// 128x128 tile, 4 waves (2x2 of 64x64), BK=32, mfma_f32_16x16x32_bf16.
template<int MODE>
__global__ __launch_bounds__(256) void gemm_k(
    const unsigned short* __restrict__ A, const unsigned short* __restrict__ W,
    const float* __restrict__ bias, const float* __restrict__ pe,
    const int* __restrict__ tok, unsigned short* __restrict__ outb,
    float* __restrict__ outf, int M, int N, int K)
{
  __shared__ unsigned short As[128*40];  // +8 pad keeps 16B align, breaks bank stride
  __shared__ unsigned short Bs[128*40];
  const int t = threadIdx.x;
  const int tn = blockIdx.x * 128;
  const int tm = blockIdx.y * 128;
  const int wave = t >> 6, lane = t & 63;
  const int wr = (wave >> 1) * 64, wc = (wave & 1) * 64;
  const int lr = lane & 15, lg = lane >> 4;

  f32x4 acc[4][4] = {};

  const int r0 = t >> 2;          // row 0..63 (chunk 0) / +64 (chunk 1)
  const int c0 = (t & 3) * 8;     // k-offset within BK=32

  for (int k0 = 0; k0 < K; k0 += 32){
    u16x8 ra0 = *(const u16x8*)(A + (size_t)(tm + r0) * K + k0 + c0);
    u16x8 ra1 = *(const u16x8*)(A + (size_t)(tm + 64 + r0) * K + k0 + c0);
    u16x8 rb0 = *(const u16x8*)(W + (size_t)(tn + r0) * K + k0 + c0);
    u16x8 rb1 = *(const u16x8*)(W + (size_t)(tn + 64 + r0) * K + k0 + c0);
    __syncthreads();
    *(u16x8*)&As[r0 * 40 + c0] = ra0;
    *(u16x8*)&As[(64 + r0) * 40 + c0] = ra1;
    *(u16x8*)&Bs[r0 * 40 + c0] = rb0;
    *(u16x8*)&Bs[(64 + r0) * 40 + c0] = rb1;
    __syncthreads();
    bf16x8 av[4], bv[4];
    #pragma unroll
    for (int mi = 0; mi < 4; mi++) av[mi] = *(const bf16x8*)&As[(wr + mi*16 + lr)*40 + lg*8];
    #pragma unroll
    for (int ni = 0; ni < 4; ni++) bv[ni] = *(const bf16x8*)&Bs[(wc + ni*16 + lr)*40 + lg*8];
    #pragma unroll
    for (int mi = 0; mi < 4; mi++)
      #pragma unroll
      for (int ni = 0; ni < 4; ni++)
        acc[mi][ni] = __builtin_amdgcn_mfma_f32_16x16x32_bf16(av[mi], bv[ni], acc[mi][ni], 0, 0, 0);
  }

  // epilogue: C/D layout col=lane&15, row=(lane>>4)*4+jj  [m89/m91-verified]
  #pragma unroll
  for (int ni = 0; ni < 4; ni++){
    const int gcol = tn + wc + ni*16 + lr;
    const float bval = bias[gcol];
    #pragma unroll
    for (int mi = 0; mi < 4; mi++){
      #pragma unroll
      for (int jj = 0; jj < 4; jj++){
        const int grow = tm + wr + mi*16 + lg*4 + jj;
        float v = acc[mi][ni][jj] + bval;
        if constexpr (MODE == 1) v += pe[(size_t)tok[grow] * 512 + gcol];
        if constexpr (MODE == 2){
          const float u = v;
          v = 0.5f * u * (1.0f + tanhf(0.7978845608f * (u + 0.044715f * u * u * u)));
        }
        if constexpr (MODE == 3) outf[(size_t)grow * N + gcol] = v;
        else                     outb[(size_t)grow * N + gcol] = f2bf(v);
      }
    }
  }
}

// ---------- attention: block per (b,h); q 147x64, k/v 49x64 ----------
__global__ __launch_bounds__(256) void attn_k(const unsigned short* __restrict__ qb,
                                              const unsigned short* __restrict__ kv,
                                              unsigned short* __restrict__ attnout)
{
  const int b = blockIdx.x >> 3, h = blockIdx.x & 7;
  __shared__ float ks[49][64];
  __shared__ float vs[49][64];
  __shared__ float pwt[147][49];
  __shared__ float inv_[147];
  const int t = threadIdx.x;
  for (int idx = t; idx < 49*64; idx += 256){
    const int j = idx >> 6, d = idx & 63;
    const size_t base = (size_t)(b*64 + j)*1024 + h*64 + d;
    ks[j][d] = bf2f(kv[base]);
    vs[j][d] = bf2f(kv[base + 512]);
  }
  __syncthreads();
  if (t < 147){
    float qv[64];
    const unsigned short* qp = qb + (size_t)(b*160 + t)*512 + h*64;
    #pragma unroll
    for (int d = 0; d < 64; d++) qv[d] = bf2f(qp[d]);
    for (int j = 0; j < 49; j++){
      float s = 0.0f;
      #pragma unroll
      for (int d = 0; d < 64; d++) s += qv[d] * ks[j][d];
      pwt[t][j] = s * 0.125f;   // 1/sqrt(64)
    }
    float m = -1e30f;
    for (int j = 0; j < 49; j++) m = fmaxf(m, pwt[t][j]);
    float sum = 0.0f;
    for (int j = 0; j < 49; j++){ const float e = __expf(pwt[t][j] - m); pwt[t][j] = e; sum += e; }
    inv_[t] = 1.0f / sum;
  }
  __syncthreads();
  for (int idx = t; idx < 147*64; idx += 256){
    const int i = idx >> 6, d = idx & 63;
    float s = 0.0f;
    for (int j = 0; j < 49; j++) s += pwt[i][j] * vs[j][d];
    s *= inv_[i];
    attnout[(size_t)(b*160 + i)*512 + h*64 + d] = f2bf(s);
  }
}

// ---------- final: three images + per-block |err| partials in one pass over x ----------
__global__ __launch_bounds__(256) void finalize_k(const float* __restrict__ x, const int* __restrict__ slot,
                           const float* __restrict__ pred, const float* __restrict__ noise,
                           float* __restrict__ out, float* __restrict__ partial)
{
  const int idx = blockIdx.x * 256 + threadIdx.x;   // < 9,633,792
  const int w = idx % 224;
  const int h = (idx / 224) % 224;
  const int c = (idx / (224*224)) % 3;
  const int b = idx / (224*224*3);
  const float xv = x[idx];
  const int p = (h >> 4) * 14 + (w >> 4);
  const int s = slot[b*196 + p];
  float rec = xv, noi = xv, mim = xv, a = 0.0f;
  if (s >= 0){
    const int d = (h & 15)*48 + (w & 15)*3 + c;
    rec = pred[(size_t)(b*160 + s)*768 + d];
    noi = noise[(size_t)(b*147 + s)*768 + d];
    mim = 1.0f;
    a = fabsf(rec - xv);
  }
  out[idx] = rec;
  out[9633792 + idx] = noi;
  out[19267585 + idx] = mim;
  // wave reduce, then cross-wave via LDS, one store per block (no atomics)
  #pragma unroll
  for (int o = 32; o > 0; o >>= 1) a += __shfl_down(a, o);
  __shared__ float wsum[4];
  if ((threadIdx.x & 63) == 0) wsum[threadIdx.x >> 6] = a;
  __syncthreads();
  if (threadIdx.x == 0)
    partial[blockIdx.x] = wsum[0] + wsum[1] + wsum[2] + wsum[3];
}

// single-block reduce of 37632 partials -> mse scalar
__global__ __launch_bounds__(256) void mse_reduce(const float* __restrict__ partial, float* __restrict__ out){
  float a = 0.0f;
  for (int i = threadIdx.x; i < 37632; i += 256) a += partial[i];
  #pragma unroll
  for (int o = 32; o > 0; o >>= 1) a += __shfl_down(a, o);
  __shared__ float wsum[4];
  if ((threadIdx.x & 63) == 0) wsum[threadIdx.x >> 6] = a;
  __syncthreads();
  if (threadIdx.x == 0)
    out[19267584] = (wsum[0] + wsum[1] + wsum[2] + wsum[3]) * (1.0f / 7225344.0f);  // / (64*147*768)
}

// ---------- launch ----------
extern "C" void kernel_launch(void* const* d_in, const int* in_sizes, int n_in,
                              void* d_out, int out_size, void* d_ws, size_t ws_size,
                              hipStream_t stream)
{
  const float* x     = (const float*)d_in[0];
  const int*   shuf  = (const int*)d_in[1];
  const float* W_pe  = (const float*)d_in[2];
  const float* b_pe  = (const float*)d_in[3];
  const float* pos   = (const float*)d_in[4];
  const float* encW  = (const float*)d_in[5];
  const float* encB  = (const float*)d_in[6];
  const float* inW   = (const float*)d_in[7];
  const float* inB   = (const float*)d_in[8];
  const float* outW  = (const float*)d_in[9];
  const float* outB  = (const float*)d_in[10];
  const float* headW = (const float*)d_in[11];
  const float* headB = (const float*)d_in[12];
  const float* noise = (const float*)d_in[13];
  float* out = (float*)d_out;

  char* ws = (char*)d_ws;
  size_t cur = 0;
  auto alloc = [&](size_t bytes){ size_t o = cur; cur += (bytes + 255) & ~(size_t)255; return o; };

  int*   slot  = (int*)(ws + alloc(64*196*4));
  int*   tokm  = (int*)(ws + alloc(10240*4));
  int*   toku  = (int*)(ws + alloc(4096*4));
  float* partial = (float*)(ws + alloc(37632*4));
  unsigned short* wpe_b   = (unsigned short*)(ws + alloc((size_t)393216*2));
  unsigned short* encw_b  = (unsigned short*)(ws + alloc((size_t)262144*2));
  unsigned short* inw_b   = (unsigned short*)(ws + alloc((size_t)786432*2));
  unsigned short* outw_b  = (unsigned short*)(ws + alloc((size_t)262144*2));
  unsigned short* headw_b = (unsigned short*)(ws + alloc((size_t)393216*2));
  // R0: maskA(15728640B) | unmaskA(6291456B) | masktok(10485760B); later attnout, then pred alias it
  char* R0 = ws + alloc(32505856);
  unsigned short* maskA   = (unsigned short*)R0;
  unsigned short* unmaskA = (unsigned short*)(R0 + 15728640);
  unsigned short* masktok = (unsigned short*)(R0 + 22020096);
  unsigned short* attnout = (unsigned short*)R0;   // alive attention..GEMM6; maskA/unmaskA/masktok dead by then
  float*          pred    = (float*)R0;            // alive GEMM7..finalize; attnout dead by then
  unsigned short* umtok = (unsigned short*)(ws + alloc((size_t)2097152*2));
  unsigned short* enc   = (unsigned short*)(ws + alloc((size_t)2097152*2));
  unsigned short* qb    = (unsigned short*)(ws + alloc((size_t)5242880*2));
  unsigned short* kvb   = (unsigned short*)(ws + alloc((size_t)4194304*2));
  unsigned short* proj  = (unsigned short*)(ws + alloc((size_t)5242880*2));

  init_misc<<<50, 256, 0, stream>>>(slot);
  scatter_slots<<<(64*147 + 255)/256, 256, 0, stream>>>(shuf, slot);
  conv_bf16<<<393216/256, 256, 0, stream>>>(W_pe, wpe_b, 393216);
  conv_bf16<<<262144/256, 256, 0, stream>>>(encW, encw_b, 262144);
  conv_bf16<<<786432/256, 256, 0, stream>>>(inW, inw_b, 786432);
  conv_bf16<<<262144/256, 256, 0, stream>>>(outW, outw_b, 262144);
  conv_bf16<<<393216/256, 256, 0, stream>>>(headW, headw_b, 393216);
  patchify<<<64*224, 256, 0, stream>>>(x, shuf, maskA, unmaskA, tokm, toku);

  // unmask_tokens = unmaskA @ W_pe^T + b_pe + pe[tok]
  gemm_k<1><<<dim3(4,32), 256, 0, stream>>>(unmaskA, wpe_b, b_pe, pos, toku, umtok, nullptr, 4096, 512, 768);
  // encoded = gelu(unmask_tokens @ enc_W^T + enc_b)
  gemm_k<2><<<dim3(4,32), 256, 0, stream>>>(umtok, encw_b, encB, nullptr, nullptr, enc, nullptr, 4096, 512, 512);
  // mask_tokens = maskA @ W_pe^T + b_pe + pe[tok]
  gemm_k<1><<<dim3(4,80), 256, 0, stream>>>(maskA, wpe_b, b_pe, pos, tokm, masktok, nullptr, 10240, 512, 768);
  // q = mask_tokens @ Wq^T + bq
  gemm_k<0><<<dim3(4,80), 256, 0, stream>>>(masktok, inw_b, inB, nullptr, nullptr, qb, nullptr, 10240, 512, 512);
  // kv = encoded @ [Wk;Wv]^T + [bk;bv]
  gemm_k<0><<<dim3(8,32), 256, 0, stream>>>(enc, inw_b + (size_t)512*512, inB + 512, nullptr, nullptr, kvb, nullptr, 4096, 1024, 512);
  attn_k<<<512, 256, 0, stream>>>(qb, kvb, attnout);
  // proj = attn_out @ out_w^T + out_b
  gemm_k<0><<<dim3(4,80), 256, 0, stream>>>(attnout, outw_b, outB, nullptr, nullptr, proj, nullptr, 10240, 512, 512);
  // pred = proj @ head_W^T + head_b  (f32 out)
  gemm_k<3><<<dim3(6,80), 256, 0, stream>>>(proj, headw_b, headB, nullptr, nullptr, nullptr, pred, 10240, 768, 512);

  finalize_k<<<37632, 256, 0, stream>>>(x, slot, pred, noise, out, partial);
  mse_reduce<<<1, 256, 0, stream>>>(partial, out);
}

// Round 3
// 258.847 us; speedup vs baseline: 8.3079x; 1.1892x over previous
//
#include <hip/hip_runtime.h>
#include <math.h>

typedef __attribute__((ext_vector_type(8))) __bf16 bf16x8;
typedef __attribute__((ext_vector_type(8))) unsigned short u16x8;
typedef __attribute__((ext_vector_type(4))) float f32x4;

typedef unsigned int as1_u32 __attribute__((address_space(1)));
typedef unsigned int as3_u32 __attribute__((address_space(3)));

// ---------- helpers ----------
__device__ __forceinline__ float bf2f(unsigned short h){
  return __uint_as_float(((unsigned int)h) << 16);
}
__device__ __forceinline__ unsigned short f2bf(float f){
  unsigned int u = __float_as_uint(f);
  unsigned int r = (u + 0x7FFFu + ((u >> 16) & 1u)) >> 16;  // RNE
  return (unsigned short)r;
}

#if __has_builtin(__builtin_amdgcn_global_load_lds)
#define HAVE_GLOAD_LDS 1
// global -> LDS direct, 16B per lane. LDS dest is wave-uniform base + lane*16.
__device__ __forceinline__ void gload16(const void* g, void* l){
  __builtin_amdgcn_global_load_lds((const as1_u32*)(unsigned long long)g,
                                   (as3_u32*)l, 16, 0, 0);
}
#else
#define HAVE_GLOAD_LDS 0
#endif

// ---------- init / scatter ----------
__global__ void init_misc(int* slot){
  int i = blockIdx.x * 256 + threadIdx.x;
  if (i < 64*196) slot[i] = -1;
}

__global__ void scatter_slots(const int* __restrict__ shuf, int* __restrict__ slot){
  int i = blockIdx.x * 256 + threadIdx.x;
  if (i >= 64*147) return;
  int b = i / 147, j = i % 147;
  slot[b*196 + shuf[b*196 + j]] = j;
}

// all five weight matrices -> one bf16 buffer (wcat)
__global__ void conv_all(const float* __restrict__ s0, const float* __restrict__ s1,
                         const float* __restrict__ s2, const float* __restrict__ s3,
                         const float* __restrict__ s4, unsigned short* __restrict__ dst){
  int i = blockIdx.x * 256 + threadIdx.x;   // < 2097152
  float v;
  if      (i <  393216) v = s0[i];
  else if (i <  655360) v = s1[i -  393216];
  else if (i < 1441792) v = s2[i -  655360];
  else if (i < 1703936) v = s3[i - 1441792];
  else                  v = s4[i - 1703936];
  dst[i] = f2bf(v);
}

// ---------- patchify + gather into padded bf16 A-matrices ----------
// rows 0..10239: masked tokens (b,i<160; valid i<147); rows 10240..14335: unmasked (b,u<64; valid u<49)
__global__ __launch_bounds__(256) void patchify(const float* __restrict__ x, const int* __restrict__ shuf,
                         unsigned short* __restrict__ maskA, unsigned short* __restrict__ unmaskA,
                         int* __restrict__ tokcat)
{
  const int blk = blockIdx.x;
  const int b = blk / 224, ip = blk % 224;
  unsigned short* dst;
  int p = 0, valid;
  if (ip < 160){
    valid = (ip < 147);
    if (valid) p = shuf[b*196 + ip];
    dst = maskA + (size_t)(b*160 + ip) * 768;
    if (threadIdx.x == 0) tokcat[b*160 + ip] = p;
  } else {
    const int u = ip - 160;
    valid = (u < 49);
    if (valid) p = shuf[b*196 + 147 + u];
    dst = unmaskA + (size_t)(b*64 + u) * 768;
    if (threadIdx.x == 0) tokcat[10240 + b*64 + u] = p;
  }
  const int gh = p / 14, gw = p % 14;
  const float* xb = x + (size_t)b * 3*224*224;
  for (int d = threadIdx.x; d < 768; d += 256){
    float v = 0.0f;
    if (valid){
      const int c = d % 3, pwi = (d/3) & 15, phi = d / 48;
      v = xb[(size_t)c*224*224 + (size_t)(gh*16+phi)*224 + (gw*16+pwi)];
    }
    dst[d] = f2bf(v);
  }
}

// ---------- bf16 MFMA GEMM: C[M,N] = A[M,K] @ W[N,K]^T + bias (+epilogue) ----------
// MODE 0: bias -> bf16.  MODE 1: bias + pos_embed[tok[row]] -> bf16.
// MODE 2: bias + gelu(tanh) -> bf16.  MODE 3: bias -> f32.
// m97 structure: 128x128 tile, 4 waves (2x2 of 64x64), BK=32, global_load_lds w=16, linear LDS.
template<int MODE>
__global__ __launch_bounds__(256) void gemm_k(
    const unsigned short* __restrict__ A, const unsigned short* __restrict__ W,
    const float* __restrict__ bias, const float* __restrict__ pe,
    const int* __restrict__ tok, unsigned short* __restrict__ outb,
    float* __restrict__ outf, int M, int N, int K)
{
  __shared__ unsigned short As[128*32];
  __shared__ unsigned short Bs[128*32];
  const int t = threadIdx.x;
  const int tn = blockIdx.x * 128;
  const int tm = blockIdx.y * 128;
  const int wave = t >> 6, lane = t & 63;
  const int wr = (wave >> 1) * 64, wc = (wave & 1) * 64;
  const int lr = lane & 15, lg = lane >> 4;

  f32x4 acc[4][4] = {};

#if HAVE_GLOAD_LDS
  // wave w stages rows [w*32, w*32+32) of each tile; 2 loads of 16 rows each
  const int srow = lane >> 2;          // 0..15 within a 16-row chunk
  const int scol = (lane & 3) * 8;     // k-offset (elements) within BK=32
  const unsigned short* Ag = A + (size_t)(tm + wave*32 + srow) * K + scol;
  const unsigned short* Bg = W + (size_t)(tn + wave*32 + srow) * K + scol;
  unsigned short* Al = As + wave*32*32;   // wave-uniform LDS bases
  unsigned short* Bl = Bs + wave*32*32;
  const size_t rstep = (size_t)16 * K;

  for (int k0 = 0; k0 < K; k0 += 32){
    __syncthreads();                 // prior iteration's LDS reads complete
    gload16(Ag + k0,         Al);
    gload16(Ag + k0 + rstep, Al + 16*32);
    gload16(Bg + k0,         Bl);
    gload16(Bg + k0 + rstep, Bl + 16*32);
    __syncthreads();                 // drains vmcnt(0): tiles visible
    bf16x8 av[4], bv[4];
    #pragma unroll
    for (int mi = 0; mi < 4; mi++) av[mi] = *(const bf16x8*)&As[(wr + mi*16 + lr)*32 + lg*8];
    #pragma unroll
    for (int ni = 0; ni < 4; ni++) bv[ni] = *(const bf16x8*)&Bs[(wc + ni*16 + lr)*32 + lg*8];
    #pragma unroll
    for (int mi = 0; mi < 4; mi++)
      #pragma unroll
      for (int ni = 0; ni < 4; ni++)
        acc[mi][ni] = __builtin_amdgcn_mfma_f32_16x16x32_bf16(av[mi], bv[ni], acc[mi][ni], 0, 0, 0);
  }
#else
  const int r0 = t >> 2;
  const int c0 = (t & 3) * 8;
  for (int k0 = 0; k0 < K; k0 += 32){
    u16x8 ra0 = *(const u16x8*)(A + (size_t)(tm + r0) * K + k0 + c0);
    u16x8 ra1 = *(const u16x8*)(A + (size_t)(tm + 64 + r0) * K + k0 + c0);
    u16x8 rb0 = *(const u16x8*)(W + (size_t)(tn + r0) * K + k0 + c0);
    u16x8 rb1 = *(const u16x8*)(W + (size_t)(tn + 64 + r0) * K + k0 + c0);
    __syncthreads();
    *(u16x8*)&As[r0 * 32 + c0] = ra0;
    *(u16x8*)&As[(64 + r0) * 32 + c0] = ra1;
    *(u16x8*)&Bs[r0 * 32 + c0] = rb0;
    *(u16x8*)&Bs[(64 + r0) * 32 + c0] = rb1;
    __syncthreads();
    bf16x8 av[4], bv[4];
    #pragma unroll
    for (int mi = 0; mi < 4; mi++) av[mi] = *(const bf16x8*)&As[(wr + mi*16 + lr)*32 + lg*8];
    #pragma unroll
    for (int ni = 0; ni < 4; ni++) bv[ni] = *(const bf16x8*)&Bs[(wc + ni*16 + lr)*32 + lg*8];
    #pragma unroll
    for (int mi = 0; mi < 4; mi++)
      #pragma unroll
      for (int ni = 0; ni < 4; ni++)
        acc[mi][ni] = __builtin_amdgcn_mfma_f32_16x16x32_bf16(av[mi], bv[ni], acc[mi][ni], 0, 0, 0);
  }
#endif

  // epilogue: C/D layout col=lane&15, row=(lane>>4)*4+jj  [m89/m91-verified]
  #pragma unroll
  for (int ni = 0; ni < 4; ni++){
    const int gcol = tn + wc + ni*16 + lr;
    const float bval = bias[gcol];
    #pragma unroll
    for (int mi = 0; mi < 4; mi++){
      #pragma unroll
      for (int jj = 0; jj < 4; jj++){
        const int grow = tm + wr + mi*16 + lg*4 + jj;
        float v = acc[mi][ni][jj] + bval;
        if constexpr (MODE == 1) v += pe[(size_t)tok[grow] * 512 + gcol];
        if constexpr (MODE == 2){
          const float u = v;
          v = 0.5f * u * (1.0f + tanhf(0.7978845608f * (u + 0.044715f * u * u * u)));
        }
        if constexpr (MODE == 3) outf[(size_t)grow * N + gcol] = v;
        else                     outb[(size_t)grow * N + gcol] = f2bf(v);
      }
    }
  }
}

// ---------- attention: block per (b,h); q 147x64, k/v 49x64 ----------
__global__ __launch_bounds__(256) void attn_k(const unsigned short* __restrict__ qb,
                                              const unsigned short* __restrict__ kv,
                                              unsigned short* __restrict__ attnout)
{
  const int b = blockIdx.x >> 3, h = blockIdx.x & 7;
  __shared__ float ks[49][64];
  __shared__ float vs[49][64];
  __shared__ float pwt[147][49];
  __shared__ float inv_[147];
  const int t = threadIdx.x;
  for (int idx = t; idx < 49*64; idx += 256){
    const int j = idx >> 6, d = idx & 63;
    const size_t base = (size_t)(b*64 + j)*1024 + h*64 + d;
    ks[j][d] = bf2f(kv[base]);
    vs[j][d] = bf2f(kv[base + 512]);
  }
  __syncthreads();
  if (t < 147){
    float qv[64];
    const unsigned short* qp = qb + (size_t)(b*160 + t)*512 + h*64;
    #pragma unroll
    for (int d = 0; d < 64; d++) qv[d] = bf2f(qp[d]);
    for (int j = 0; j < 49; j++){
      float s = 0.0f;
      #pragma unroll
      for (int d = 0; d < 64; d++) s += qv[d] * ks[j][d];
      pwt[t][j] = s * 0.125f;   // 1/sqrt(64)
    }
    float m = -1e30f;
    for (int j = 0; j < 49; j++) m = fmaxf(m, pwt[t][j]);
    float sum = 0.0f;
    for (int j = 0; j < 49; j++){ const float e = __expf(pwt[t][j] - m); pwt[t][j] = e; sum += e; }
    inv_[t] = 1.0f / sum;
  }
  __syncthreads();
  for (int idx = t; idx < 147*64; idx += 256){
    const int i = idx >> 6, d = idx & 63;
    float s = 0.0f;
    for (int j = 0; j < 49; j++) s += pwt[i][j] * vs[j][d];
    s *= inv_[i];
    attnout[(size_t)(b*160 + i)*512 + h*64 + d] = f2bf(s);
  }
}

// ---------- final: three images + per-block |err| partials; 4 pixels/thread ----------
__global__ __launch_bounds__(256) void finalize_k(const float* __restrict__ x, const int* __restrict__ slot,
                           const float* __restrict__ pred, const float* __restrict__ noise,
                           float* __restrict__ out, float* __restrict__ partial)
{
  const int i4 = blockIdx.x * 256 + threadIdx.x;   // < 2,408,448
  const int idx = i4 * 4;
  const int w = idx % 224;                          // 4-aligned; all 4 pixels share h,c,b and patch
  const int h = (idx / 224) % 224;
  const int c = (idx / 50176) % 3;
  const int b = idx / 150528;
  const float4 xv = *(const float4*)(x + idx);
  const int p = (h >> 4) * 14 + (w >> 4);
  const int s = slot[b*196 + p];
  float4 rec = xv, noi = xv, mim = xv;
  float a = 0.0f;
  if (s >= 0){
    const int d = (h & 15)*48 + (w & 15)*3 + c;
    const size_t pb = (size_t)(b*160 + s)*768 + d;
    const size_t nb = (size_t)(b*147 + s)*768 + d;
    rec = make_float4(pred[pb], pred[pb+3], pred[pb+6], pred[pb+9]);
    noi = make_float4(noise[nb], noise[nb+3], noise[nb+6], noise[nb+9]);
    mim = make_float4(1.0f, 1.0f, 1.0f, 1.0f);
    a = fabsf(rec.x - xv.x) + fabsf(rec.y - xv.y) + fabsf(rec.z - xv.z) + fabsf(rec.w - xv.w);
  }
  *(float4*)(out + idx) = rec;
  *(float4*)(out + 9633792 + idx) = noi;            // 9633792 % 4 == 0 -> 16B aligned
  float* m3 = out + 19267585 + idx;                 // odd float offset: scalar stores
  m3[0] = mim.x; m3[1] = mim.y; m3[2] = mim.z; m3[3] = mim.w;
  // wave reduce, then cross-wave via LDS, one store per block (no atomics)
  #pragma unroll
  for (int o = 32; o > 0; o >>= 1) a += __shfl_down(a, o);
  __shared__ float wsum[4];
  if ((threadIdx.x & 63) == 0) wsum[threadIdx.x >> 6] = a;
  __syncthreads();
  if (threadIdx.x == 0)
    partial[blockIdx.x] = wsum[0] + wsum[1] + wsum[2] + wsum[3];
}

// single-block reduce of 9408 partials -> mse scalar
__global__ __launch_bounds__(256) void mse_reduce(const float* __restrict__ partial, float* __restrict__ out){
  float a = 0.0f;
  for (int i = threadIdx.x; i < 9408; i += 256) a += partial[i];
  #pragma unroll
  for (int o = 32; o > 0; o >>= 1) a += __shfl_down(a, o);
  __shared__ float wsum[4];
  if ((threadIdx.x & 63) == 0) wsum[threadIdx.x >> 6] = a;
  __syncthreads();
  if (threadIdx.x == 0)
    out[19267584] = (wsum[0] + wsum[1] + wsum[2] + wsum[3]) * (1.0f / 7225344.0f);  // / (64*147*768)
}

// ---------- launch ----------
extern "C" void kernel_launch(void* const* d_in, const int* in_sizes, int n_in,
                              void* d_out, int out_size, void* d_ws, size_t ws_size,
                              hipStream_t stream)
{
  const float* x     = (const float*)d_in[0];
  const int*   shuf  = (const int*)d_in[1];
  const float* W_pe  = (const float*)d_in[2];
  const float* b_pe  = (const float*)d_in[3];
  const float* pos   = (const float*)d_in[4];
  const float* encW  = (const float*)d_in[5];
  const float* encB  = (const float*)d_in[6];
  const float* inW   = (const float*)d_in[7];
  const float* inB   = (const float*)d_in[8];
  const float* outW  = (const float*)d_in[9];
  const float* outB  = (const float*)d_in[10];
  const float* headW = (const float*)d_in[11];
  const float* headB = (const float*)d_in[12];
  const float* noise = (const float*)d_in[13];
  float* out = (float*)d_out;

  char* ws = (char*)d_ws;
  size_t cur = 0;
  auto alloc = [&](size_t bytes){ size_t o = cur; cur += (bytes + 255) & ~(size_t)255; return o; };

  int*   slot    = (int*)(ws + alloc(64*196*4));
  int*   tokcat  = (int*)(ws + alloc(14336*4));
  float* partial = (float*)(ws + alloc(9408*4));
  // wcat: wpe | encw | inw | outw | headw  (bf16), offsets in elements below
  unsigned short* wcat = (unsigned short*)(ws + alloc((size_t)2097152*2));
  unsigned short* wpe_b   = wcat;
  unsigned short* encw_b  = wcat +  393216;
  unsigned short* inw_b   = wcat +  655360;
  unsigned short* outw_b  = wcat + 1441792;
  unsigned short* headw_b = wcat + 1703936;
  // R0: maskA(15,728,640B) | unmaskA(6,291,456B) | tokens(14,680,064B)
  // later: attnout (10.5MB) aliases base; pred (31.5MB f32) aliases base
  char* R0 = ws + alloc(36765696);
  unsigned short* maskA   = (unsigned short*)R0;
  unsigned short* unmaskA = (unsigned short*)(R0 + 15728640);
  unsigned short* tokens  = (unsigned short*)(R0 + 22020096);  // [14336][512] bf16
  unsigned short* attnout = (unsigned short*)R0;   // alive attn..projGEMM; maskA/unmaskA dead by then
  float*          pred    = (float*)R0;            // alive headGEMM..finalize; attnout dead by then
  unsigned short* enc   = (unsigned short*)(ws + alloc((size_t)2097152*2));
  unsigned short* qb    = (unsigned short*)(ws + alloc((size_t)5242880*2));
  unsigned short* kvb   = (unsigned short*)(ws + alloc((size_t)4194304*2));
  unsigned short* proj  = (unsigned short*)(ws + alloc((size_t)5242880*2));

  init_misc<<<49, 256, 0, stream>>>(slot);
  scatter_slots<<<37, 256, 0, stream>>>(shuf, slot);
  conv_all<<<8192, 256, 0, stream>>>(W_pe, encW, inW, outW, headW, wcat);
  patchify<<<64*224, 256, 0, stream>>>(x, shuf, maskA, unmaskA, tokcat);

  // tokens[0:10240] = mask_tokens, tokens[10240:14336] = unmask_tokens  (merged pe-GEMM)
  gemm_k<1><<<dim3(4,112), 256, 0, stream>>>(maskA, wpe_b, b_pe, pos, tokcat, tokens, nullptr, 14336, 512, 768);
  // encoded = gelu(unmask_tokens @ enc_W^T + enc_b)
  gemm_k<2><<<dim3(4,32), 256, 0, stream>>>(tokens + (size_t)10240*512, encw_b, encB, nullptr, nullptr, enc, nullptr, 4096, 512, 512);
  // q = mask_tokens @ Wq^T + bq
  gemm_k<0><<<dim3(4,80), 256, 0, stream>>>(tokens, inw_b, inB, nullptr, nullptr, qb, nullptr, 10240, 512, 512);
  // kv = encoded @ [Wk;Wv]^T + [bk;bv]
  gemm_k<0><<<dim3(8,32), 256, 0, stream>>>(enc, inw_b + (size_t)512*512, inB + 512, nullptr, nullptr, kvb, nullptr, 4096, 1024, 512);
  attn_k<<<512, 256, 0, stream>>>(qb, kvb, attnout);
  // proj = attn_out @ out_w^T + out_b
  gemm_k<0><<<dim3(4,80), 256, 0, stream>>>(attnout, outw_b, outB, nullptr, nullptr, proj, nullptr, 10240, 512, 512);
  // pred = proj @ head_W^T + head_b  (f32 out)
  gemm_k<3><<<dim3(6,80), 256, 0, stream>>>(proj, headw_b, headB, nullptr, nullptr, nullptr, pred, 10240, 768, 512);

  finalize_k<<<9408, 256, 0, stream>>>(x, slot, pred, noise, out, partial);
  mse_reduce<<<1, 256, 0, stream>>>(partial, out);
}

// Round 4
// 253.034 us; speedup vs baseline: 8.4987x; 1.0230x over previous
//
#include <hip/hip_runtime.h>
#include <math.h>

typedef __attribute__((ext_vector_type(8))) __bf16 bf16x8;
typedef __attribute__((ext_vector_type(8))) unsigned short u16x8;
typedef __attribute__((ext_vector_type(4))) float f32x4;

typedef unsigned int as1_u32 __attribute__((address_space(1)));
typedef unsigned int as3_u32 __attribute__((address_space(3)));

// ---------- helpers ----------
__device__ __forceinline__ float bf2f(unsigned short h){
  return __uint_as_float(((unsigned int)h) << 16);
}
__device__ __forceinline__ unsigned short f2bf(float f){
  unsigned int u = __float_as_uint(f);
  unsigned int r = (u + 0x7FFFu + ((u >> 16) & 1u)) >> 16;  // RNE
  return (unsigned short)r;
}

#if __has_builtin(__builtin_amdgcn_global_load_lds)
#define HAVE_GLOAD_LDS 1
__device__ __forceinline__ void gload16(const void* g, void* l){
  __builtin_amdgcn_global_load_lds((const as1_u32*)(unsigned long long)g,
                                   (as3_u32*)l, 16, 0, 0);
}
#else
#define HAVE_GLOAD_LDS 0
#endif

// ---------- init / scatter ----------
__global__ void init_misc(int* slot){
  int i = blockIdx.x * 256 + threadIdx.x;
  if (i < 64*196) slot[i] = -1;
}

__global__ void scatter_slots(const int* __restrict__ shuf, int* __restrict__ slot){
  int i = blockIdx.x * 256 + threadIdx.x;
  if (i >= 64*147) return;
  int b = i / 147, j = i % 147;
  slot[b*196 + shuf[b*196 + j]] = j;
}

// encW | inW | headW -> bf16 wcat
__global__ void conv_all(const float* __restrict__ s0, const float* __restrict__ s1,
                         const float* __restrict__ s2, unsigned short* __restrict__ dst){
  int i = blockIdx.x * 256 + threadIdx.x;   // < 1441792
  float v;
  if      (i <  262144) v = s0[i];
  else if (i < 1048576) v = s1[i -  262144];
  else                  v = s2[i - 1048576];
  dst[i] = f2bf(v);
}

// W_pe [512][768] -> WpeT [768][512] bf16 ; out_w [512][512] -> outwT [512][512] bf16
__global__ __launch_bounds__(256) void transpose_both(const float* __restrict__ Wpe, const float* __restrict__ outw,
                               unsigned short* __restrict__ WpeT, unsigned short* __restrict__ outwT){
  int bid = blockIdx.x;
  const float* src; unsigned short* dst; int R, C, bx, by;
  if (bid < 384){ src = Wpe;  dst = WpeT;  R = 512; C = 768; bx = bid % 24; by = bid / 24; }
  else { bid -= 384; src = outw; dst = outwT; R = 512; C = 512; bx = bid % 16; by = bid / 16; }
  __shared__ float tile[32][33];
  const int tx = threadIdx.x & 31, ty = threadIdx.x >> 5;
  #pragma unroll
  for (int i = 0; i < 4; i++)
    tile[ty + i*8][tx] = src[(size_t)(by*32 + ty + i*8)*C + bx*32 + tx];
  __syncthreads();
  #pragma unroll
  for (int i = 0; i < 4; i++)
    dst[(size_t)(bx*32 + ty + i*8)*R + by*32 + tx] = f2bf(tile[tx][ty + i*8]);
}

// pe2b = bf16(pos + b_pe) [196x512, rows 196..255 untouched]; bh32 = headW@outb + headb [768]
__global__ __launch_bounds__(256) void prep_small(const float* __restrict__ pos, const float* __restrict__ b_pe,
                            const float* __restrict__ headW, const float* __restrict__ outb,
                            const float* __restrict__ headb,
                            unsigned short* __restrict__ pe2b, float* __restrict__ bh32){
  const int blk = blockIdx.x, t = threadIdx.x;
  if (blk < 392){
    const int i = blk*256 + t;          // < 100352 exactly
    pe2b[i] = f2bf(pos[i] + b_pe[i & 511]);
  } else {
    const int r = (blk - 392)*64 + (t >> 2);   // 0..767
    const int q4 = t & 3;
    float a = 0.0f;
    const float* hw = headW + (size_t)r*512 + q4*128;
    const float* ob = outb + q4*128;
    for (int e = 0; e < 128; e++) a += hw[e] * ob[e];
    a += __shfl_down(a, 2, 4);
    a += __shfl_down(a, 1, 4);
    if (q4 == 0) bh32[r] = a + headb[r];
  }
}

// ---------- patchify: float4 loads -> LDS repack -> 16B bf16 stores ----------
// rows 0..10239: masked (b,i<160; valid i<147); rows 10240..: unmasked (b,u<64; valid u<49)
__global__ __launch_bounds__(256) void patchify(const float* __restrict__ x, const int* __restrict__ shuf,
                         unsigned short* __restrict__ maskA, unsigned short* __restrict__ unmaskA,
                         int* __restrict__ tokcat)
{
  const int blk = blockIdx.x;
  const int b = blk / 224, ip = blk % 224;
  unsigned short* dst;
  int p = 0, valid;
  if (ip < 160){
    valid = (ip < 147);
    if (valid) p = shuf[b*196 + ip];
    dst = maskA + (size_t)(b*160 + ip) * 768;
    if (threadIdx.x == 0) tokcat[b*160 + ip] = p;
  } else {
    const int u = ip - 160;
    valid = (u < 49);
    if (valid) p = shuf[b*196 + 147 + u];
    dst = unmaskA + (size_t)(b*64 + u) * 768;
    if (threadIdx.x == 0) tokcat[10240 + b*64 + u] = p;
  }
  const int gh = p / 14, gw = p % 14;
  __shared__ float ld[768];
  const int t = threadIdx.x;
  if (valid && t < 192){
    const int seg = t >> 2, part = t & 3;
    const int c = seg >> 4, phi = seg & 15;
    const float4 v4 = *(const float4*)(x + (size_t)b*150528 + c*50176
                                       + (size_t)(gh*16 + phi)*224 + gw*16 + part*4);
    const int dbase = phi*48 + part*12 + c;   // d = phi*48 + pwi*3 + c, pwi = part*4+j
    ld[dbase]     = v4.x;
    ld[dbase + 3] = v4.y;
    ld[dbase + 6] = v4.z;
    ld[dbase + 9] = v4.w;
  }
  __syncthreads();
  if (t < 96){
    u16x8 o;
    if (valid){
      #pragma unroll
      for (int j = 0; j < 8; j++) o[j] = f2bf(ld[t*8 + j]);
    } else {
      #pragma unroll
      for (int j = 0; j < 8; j++) o[j] = 0;
    }
    *(u16x8*)&dst[t*8] = o;
  }
}

// ---------- bf16 MFMA GEMM core (m97 structure) ----------
// 128x128 tile, 4 waves (2x2 of 64x64), BK=32, global_load_lds w=16, linear LDS.
// MODE 0: +bias[col] -> bf16.  MODE 1: +pe[tok[row]*512+col] -> bf16.
// MODE 2: +pe[tok[row]*512+col], gelu -> bf16.
template<int MODE>
__global__ __launch_bounds__(256) void gemm_k(
    const unsigned short* __restrict__ A, const unsigned short* __restrict__ W,
    const float* __restrict__ bias, const float* __restrict__ pe,
    const int* __restrict__ tok, unsigned short* __restrict__ outb,
    int M, int N, int K)
{
  __shared__ unsigned short As[128*32];
  __shared__ unsigned short Bs[128*32];
  const int t = threadIdx.x;
  const int tn = blockIdx.x * 128;
  const int tm = blockIdx.y * 128;
  const int wave = t >> 6, lane = t & 63;
  const int wr = (wave >> 1) * 64, wc = (wave & 1) * 64;
  const int lr = lane & 15, lg = lane >> 4;

  f32x4 acc[4][4] = {};

#if HAVE_GLOAD_LDS
  const int srow = lane >> 2;
  const int scol = (lane & 3) * 8;
  const unsigned short* Ag = A + (size_t)(tm + wave*32 + srow) * K + scol;
  const unsigned short* Bg = W + (size_t)(tn + wave*32 + srow) * K + scol;
  unsigned short* Al = As + wave*32*32;
  unsigned short* Bl = Bs + wave*32*32;
  const size_t rstep = (size_t)16 * K;

  for (int k0 = 0; k0 < K; k0 += 32){
    __syncthreads();
    gload16(Ag + k0,         Al);
    gload16(Ag + k0 + rstep, Al + 16*32);
    gload16(Bg + k0,         Bl);
    gload16(Bg + k0 + rstep, Bl + 16*32);
    __syncthreads();
    bf16x8 av[4], bv[4];
    #pragma unroll
    for (int mi = 0; mi < 4; mi++) av[mi] = *(const bf16x8*)&As[(wr + mi*16 + lr)*32 + lg*8];
    #pragma unroll
    for (int ni = 0; ni < 4; ni++) bv[ni] = *(const bf16x8*)&Bs[(wc + ni*16 + lr)*32 + lg*8];
    #pragma unroll
    for (int mi = 0; mi < 4; mi++)
      #pragma unroll
      for (int ni = 0; ni < 4; ni++)
        acc[mi][ni] = __builtin_amdgcn_mfma_f32_16x16x32_bf16(av[mi], bv[ni], acc[mi][ni], 0, 0, 0);
  }
#else
  const int r0 = t >> 2;
  const int c0 = (t & 3) * 8;
  for (int k0 = 0; k0 < K; k0 += 32){
    u16x8 ra0 = *(const u16x8*)(A + (size_t)(tm + r0) * K + k0 + c0);
    u16x8 ra1 = *(const u16x8*)(A + (size_t)(tm + 64 + r0) * K + k0 + c0);
    u16x8 rb0 = *(const u16x8*)(W + (size_t)(tn + r0) * K + k0 + c0);
    u16x8 rb1 = *(const u16x8*)(W + (size_t)(tn + 64 + r0) * K + k0 + c0);
    __syncthreads();
    *(u16x8*)&As[r0 * 32 + c0] = ra0;
    *(u16x8*)&As[(64 + r0) * 32 + c0] = ra1;
    *(u16x8*)&Bs[r0 * 32 + c0] = rb0;
    *(u16x8*)&Bs[(64 + r0) * 32 + c0] = rb1;
    __syncthreads();
    bf16x8 av[4], bv[4];
    #pragma unroll
    for (int mi = 0; mi < 4; mi++) av[mi] = *(const bf16x8*)&As[(wr + mi*16 + lr)*32 + lg*8];
    #pragma unroll
    for (int ni = 0; ni < 4; ni++) bv[ni] = *(const bf16x8*)&Bs[(wc + ni*16 + lr)*32 + lg*8];
    #pragma unroll
    for (int mi = 0; mi < 4; mi++)
      #pragma unroll
      for (int ni = 0; ni < 4; ni++)
        acc[mi][ni] = __builtin_amdgcn_mfma_f32_16x16x32_bf16(av[mi], bv[ni], acc[mi][ni], 0, 0, 0);
  }
#endif

  // epilogue: C/D layout col=lane&15, row=(lane>>4)*4+jj
  #pragma unroll
  for (int ni = 0; ni < 4; ni++){
    const int gcol = tn + wc + ni*16 + lr;
    float bval = 0.0f;
    if constexpr (MODE == 0) bval = bias[gcol];
    #pragma unroll
    for (int mi = 0; mi < 4; mi++){
      #pragma unroll
      for (int jj = 0; jj < 4; jj++){
        const int grow = tm + wr + mi*16 + lg*4 + jj;
        float v = acc[mi][ni][jj] + bval;
        if constexpr (MODE == 1 || MODE == 2) v += pe[(size_t)tok[grow] * 512 + gcol];
        if constexpr (MODE == 2){
          const float u = v;
          v = 0.5f * u * (1.0f + tanhf(0.7978845608f * (u + 0.044715f * u * u * u)));
        }
        outb[(size_t)grow * N + gcol] = f2bf(v);
      }
    }
  }
}

// ---------- batched small GEMMs (weight folding), one launch ----------
// mode 0: bf16 out, no bias.  mode 1: f32 out + bias[col].
struct GD {
  const unsigned short* A; const unsigned short* W; const float* bias;
  unsigned short* ob; float* of; int M, N, K, mode, blk0;
};

__global__ __launch_bounds__(256) void gemm_multi(GD g0, GD g1, GD g2, GD g3, GD g4){
  const int bid = blockIdx.x;
  GD g = g0;
  if      (bid >= g4.blk0) g = g4;
  else if (bid >= g3.blk0) g = g3;
  else if (bid >= g2.blk0) g = g2;
  else if (bid >= g1.blk0) g = g1;
  const int local = bid - g.blk0;
  const int nx = g.N >> 7;
  const int tn = (local % nx) * 128;
  const int tm = (local / nx) * 128;
  const int K = g.K;

  __shared__ unsigned short As[128*32];
  __shared__ unsigned short Bs[128*32];
  const int t = threadIdx.x;
  const int wave = t >> 6, lane = t & 63;
  const int wr = (wave >> 1) * 64, wc = (wave & 1) * 64;
  const int lr = lane & 15, lg = lane >> 4;

  f32x4 acc[4][4] = {};

#if HAVE_GLOAD_LDS
  const int srow = lane >> 2;
  const int scol = (lane & 3) * 8;
  const unsigned short* Ag = g.A + (size_t)(tm + wave*32 + srow) * K + scol;
  const unsigned short* Bg = g.W + (size_t)(tn + wave*32 + srow) * K + scol;
  unsigned short* Al = As + wave*32*32;
  unsigned short* Bl = Bs + wave*32*32;
  const size_t rstep = (size_t)16 * K;
  for (int k0 = 0; k0 < K; k0 += 32){
    __syncthreads();
    gload16(Ag + k0,         Al);
    gload16(Ag + k0 + rstep, Al + 16*32);
    gload16(Bg + k0,         Bl);
    gload16(Bg + k0 + rstep, Bl + 16*32);
    __syncthreads();
    bf16x8 av[4], bv[4];
    #pragma unroll
    for (int mi = 0; mi < 4; mi++) av[mi] = *(const bf16x8*)&As[(wr + mi*16 + lr)*32 + lg*8];
    #pragma unroll
    for (int ni = 0; ni < 4; ni++) bv[ni] = *(const bf16x8*)&Bs[(wc + ni*16 + lr)*32 + lg*8];
    #pragma unroll
    for (int mi = 0; mi < 4; mi++)
      #pragma unroll
      for (int ni = 0; ni < 4; ni++)
        acc[mi][ni] = __builtin_amdgcn_mfma_f32_16x16x32_bf16(av[mi], bv[ni], acc[mi][ni], 0, 0, 0);
  }
#else
  const int r0 = t >> 2;
  const int c0 = (t & 3) * 8;
  for (int k0 = 0; k0 < K; k0 += 32){
    u16x8 ra0 = *(const u16x8*)(g.A + (size_t)(tm + r0) * K + k0 + c0);
    u16x8 ra1 = *(const u16x8*)(g.A + (size_t)(tm + 64 + r0) * K + k0 + c0);
    u16x8 rb0 = *(const u16x8*)(g.W + (size_t)(tn + r0) * K + k0 + c0);
    u16x8 rb1 = *(const u16x8*)(g.W + (size_t)(tn + 64 + r0) * K + k0 + c0);
    __syncthreads();
    *(u16x8*)&As[r0 * 32 + c0] = ra0;
    *(u16x8*)&As[(64 + r0) * 32 + c0] = ra1;
    *(u16x8*)&Bs[r0 * 32 + c0] = rb0;
    *(u16x8*)&Bs[(64 + r0) * 32 + c0] = rb1;
    __syncthreads();
    bf16x8 av[4], bv[4];
    #pragma unroll
    for (int mi = 0; mi < 4; mi++) av[mi] = *(const bf16x8*)&As[(wr + mi*16 + lr)*32 + lg*8];
    #pragma unroll
    for (int ni = 0; ni < 4; ni++) bv[ni] = *(const bf16x8*)&Bs[(wc + ni*16 + lr)*32 + lg*8];
    #pragma unroll
    for (int mi = 0; mi < 4; mi++)
      #pragma unroll
      for (int ni = 0; ni < 4; ni++)
        acc[mi][ni] = __builtin_amdgcn_mfma_f32_16x16x32_bf16(av[mi], bv[ni], acc[mi][ni], 0, 0, 0);
  }
#endif

  #pragma unroll
  for (int ni = 0; ni < 4; ni++){
    const int gcol = tn + wc + ni*16 + lr;
    const float bval = (g.mode == 1) ? g.bias[gcol] : 0.0f;
    #pragma unroll
    for (int mi = 0; mi < 4; mi++){
      #pragma unroll
      for (int jj = 0; jj < 4; jj++){
        const int grow = tm + wr + mi*16 + lg*4 + jj;
        const float v = acc[mi][ni][jj] + bval;
        if (g.mode == 1) g.of[(size_t)grow * g.N + gcol] = v;
        else             g.ob[(size_t)grow * g.N + gcol] = f2bf(v);
      }
    }
  }
}

// ---------- attention: block per (b,h); q 147x64, k/v 49x64 ----------
__global__ __launch_bounds__(256) void attn_k(const unsigned short* __restrict__ qb,
                                              const unsigned short* __restrict__ kv,
                                              unsigned short* __restrict__ attnout)
{
  const int b = blockIdx.x >> 3, h = blockIdx.x & 7;
  __shared__ float ks[49][64];
  __shared__ float vs[49][64];
  __shared__ float pwt[147][49];
  __shared__ float inv_[147];
  const int t = threadIdx.x;
  for (int idx = t; idx < 49*64; idx += 256){
    const int j = idx >> 6, d = idx & 63;
    const size_t base = (size_t)(b*64 + j)*1024 + h*64 + d;
    ks[j][d] = bf2f(kv[base]);
    vs[j][d] = bf2f(kv[base + 512]);
  }
  __syncthreads();
  if (t < 147){
    float qv[64];
    const unsigned short* qp = qb + (size_t)(b*160 + t)*512 + h*64;
    #pragma unroll
    for (int d = 0; d < 64; d++) qv[d] = bf2f(qp[d]);
    for (int j = 0; j < 49; j++){
      float s = 0.0f;
      #pragma unroll
      for (int d = 0; d < 64; d++) s += qv[d] * ks[j][d];
      pwt[t][j] = s * 0.125f;   // 1/sqrt(64)
    }
    float m = -1e30f;
    for (int j = 0; j < 49; j++) m = fmaxf(m, pwt[t][j]);
    float sum = 0.0f;
    for (int j = 0; j < 49; j++){ const float e = __expf(pwt[t][j] - m); pwt[t][j] = e; sum += e; }
    inv_[t] = 1.0f / sum;
  }
  __syncthreads();
  for (int idx = t; idx < 147*64; idx += 256){
    const int i = idx >> 6, d = idx & 63;
    float s = 0.0f;
    for (int j = 0; j < 49; j++) s += pwt[i][j] * vs[j][d];
    s *= inv_[i];
    attnout[(size_t)(b*160 + i)*512 + h*64 + d] = f2bf(s);
  }
}

// ---------- final: three images + per-block |err| partials; 4 pixels/thread ----------
__global__ __launch_bounds__(256) void finalize_k(const float* __restrict__ x, const int* __restrict__ slot,
                           const unsigned short* __restrict__ predb, const float* __restrict__ noise,
                           float* __restrict__ out, float* __restrict__ partial)
{
  const int i4 = blockIdx.x * 256 + threadIdx.x;   // < 2,408,448
  const int idx = i4 * 4;
  const int w = idx % 224;
  const int h = (idx / 224) % 224;
  const int c = (idx / 50176) % 3;
  const int b = idx / 150528;
  const float4 xv = *(const float4*)(x + idx);
  const int p = (h >> 4) * 14 + (w >> 4);
  const int s = slot[b*196 + p];
  float4 rec = xv, noi = xv, mim = xv;
  float a = 0.0f;
  if (s >= 0){
    const int d = (h & 15)*48 + (w & 15)*3 + c;
    const size_t pb = (size_t)(b*160 + s)*768 + d;
    const size_t nb = (size_t)(b*147 + s)*768 + d;
    rec = make_float4(bf2f(predb[pb]), bf2f(predb[pb+3]), bf2f(predb[pb+6]), bf2f(predb[pb+9]));
    noi = make_float4(noise[nb], noise[nb+3], noise[nb+6], noise[nb+9]);
    mim = make_float4(1.0f, 1.0f, 1.0f, 1.0f);
    a = fabsf(rec.x - xv.x) + fabsf(rec.y - xv.y) + fabsf(rec.z - xv.z) + fabsf(rec.w - xv.w);
  }
  *(float4*)(out + idx) = rec;
  *(float4*)(out + 9633792 + idx) = noi;
  float* m3 = out + 19267585 + idx;
  m3[0] = mim.x; m3[1] = mim.y; m3[2] = mim.z; m3[3] = mim.w;
  #pragma unroll
  for (int o = 32; o > 0; o >>= 1) a += __shfl_down(a, o);
  __shared__ float wsum[4];
  if ((threadIdx.x & 63) == 0) wsum[threadIdx.x >> 6] = a;
  __syncthreads();
  if (threadIdx.x == 0)
    partial[blockIdx.x] = wsum[0] + wsum[1] + wsum[2] + wsum[3];
}

__global__ __launch_bounds__(256) void mse_reduce(const float* __restrict__ partial, float* __restrict__ out){
  float a = 0.0f;
  for (int i = threadIdx.x; i < 9408; i += 256) a += partial[i];
  #pragma unroll
  for (int o = 32; o > 0; o >>= 1) a += __shfl_down(a, o);
  __shared__ float wsum[4];
  if ((threadIdx.x & 63) == 0) wsum[threadIdx.x >> 6] = a;
  __syncthreads();
  if (threadIdx.x == 0)
    out[19267584] = (wsum[0] + wsum[1] + wsum[2] + wsum[3]) * (1.0f / 7225344.0f);
}

// ---------- launch ----------
extern "C" void kernel_launch(void* const* d_in, const int* in_sizes, int n_in,
                              void* d_out, int out_size, void* d_ws, size_t ws_size,
                              hipStream_t stream)
{
  const float* x     = (const float*)d_in[0];
  const int*   shuf  = (const int*)d_in[1];
  const float* W_pe  = (const float*)d_in[2];
  const float* b_pe  = (const float*)d_in[3];
  const float* pos   = (const float*)d_in[4];
  const float* encW  = (const float*)d_in[5];
  const float* encB  = (const float*)d_in[6];
  const float* inW   = (const float*)d_in[7];
  const float* inB   = (const float*)d_in[8];
  const float* outW  = (const float*)d_in[9];
  const float* outB  = (const float*)d_in[10];
  const float* headW = (const float*)d_in[11];
  const float* headB = (const float*)d_in[12];
  const float* noise = (const float*)d_in[13];
  float* out = (float*)d_out;

  char* ws = (char*)d_ws;
  size_t cur = 0;
  auto alloc = [&](size_t bytes){ size_t o = cur; cur += (bytes + 255) & ~(size_t)255; return o; };

  int*   slot    = (int*)(ws + alloc(64*196*4));
  int*   tokcat  = (int*)(ws + alloc(14336*4));
  float* partial = (float*)(ws + alloc(9408*4));
  // wcat: encw | inw | headw (bf16)
  unsigned short* wcat    = (unsigned short*)(ws + alloc((size_t)1441792*2));
  unsigned short* encw_b  = wcat;
  unsigned short* inw_b   = wcat +  262144;   // [Wq;Wk;Wv] rows
  unsigned short* headw_b = wcat + 1048576;   // [768][512]
  unsigned short* WpeT  = (unsigned short*)(ws + alloc((size_t)393216*2));  // [768][512]
  unsigned short* outwT = (unsigned short*)(ws + alloc((size_t)262144*2));  // [512][512]
  unsigned short* Wqpe  = (unsigned short*)(ws + alloc((size_t)393216*2));  // [512][768]
  unsigned short* Wepe  = (unsigned short*)(ws + alloc((size_t)393216*2));  // [512][768]
  unsigned short* Whp   = (unsigned short*)(ws + alloc((size_t)393216*2));  // [768][512]
  unsigned short* pe2b  = (unsigned short*)(ws + alloc((size_t)131072*2));  // [256][512] bf16
  float* peq  = (float*)(ws + alloc((size_t)131072*4));                     // [256][512]
  float* pee  = (float*)(ws + alloc((size_t)131072*4));
  float* bh32 = (float*)(ws + alloc(768*4));
  // R0: maskA(15.7MB) | unmaskA(6.3MB); later attnout(10.5MB)@0, pred bf16(15.7MB)@+10.5MB
  char* R0 = ws + alloc(26214400);
  unsigned short* maskA   = (unsigned short*)R0;
  unsigned short* unmaskA = (unsigned short*)(R0 + 15728640);
  unsigned short* attnout = (unsigned short*)R0;                 // alive attn..G4 (maskA dead)
  unsigned short* predb   = (unsigned short*)(R0 + 10485760);    // alive G4..finalize
  unsigned short* enc   = (unsigned short*)(ws + alloc((size_t)2097152*2));
  unsigned short* qb    = (unsigned short*)(ws + alloc((size_t)5242880*2));
  unsigned short* kvb   = (unsigned short*)(ws + alloc((size_t)4194304*2));

  init_misc<<<49, 256, 0, stream>>>(slot);
  scatter_slots<<<37, 256, 0, stream>>>(shuf, slot);
  transpose_both<<<640, 256, 0, stream>>>(W_pe, outW, WpeT, outwT);
  conv_all<<<5632, 256, 0, stream>>>(encW, inW, headW, wcat);
  prep_small<<<404, 256, 0, stream>>>(pos, b_pe, headW, outB, headB, pe2b, bh32);
  patchify<<<64*224, 256, 0, stream>>>(x, shuf, maskA, unmaskA, tokcat);

  // weight folds, one launch:
  // T1 Wqpe = Wq @ WpeT'   (M=512,N=768,K=512) -> bf16
  // T2 Wepe = encW @ WpeT' (M=512,N=768,K=512) -> bf16
  // T3 Whp  = headW @ outwT' (M=768,N=512,K=512) -> bf16
  // T4 peq  = pe2 @ Wq^T + bq   (M=256,N=512,K=512) -> f32
  // T5 pee  = pe2 @ encW^T + encb (M=256,N=512,K=512) -> f32
  {
    GD t1 = { inw_b,  WpeT,  nullptr,     Wqpe, nullptr, 512, 768, 512, 0,  0 };
    GD t2 = { encw_b, WpeT,  nullptr,     Wepe, nullptr, 512, 768, 512, 0, 24 };
    GD t3 = { headw_b,outwT, nullptr,     Whp,  nullptr, 768, 512, 512, 0, 48 };
    GD t4 = { pe2b,   inw_b, inB,         nullptr, peq,  256, 512, 512, 1, 72 };
    GD t5 = { pe2b,   encw_b,encB,        nullptr, pee,  256, 512, 512, 1, 80 };
    gemm_multi<<<88, 256, 0, stream>>>(t1, t2, t3, t4, t5);
  }

  // q = maskA @ Wqpe^T + peq[tokm]          (M=10240,N=512,K=768)
  gemm_k<1><<<dim3(4,80), 256, 0, stream>>>(maskA, Wqpe, nullptr, peq, tokcat, qb, 10240, 512, 768);
  // enc = gelu(unmaskA @ Wepe^T + pee[toku]) (M=4096,N=512,K=768)
  gemm_k<2><<<dim3(4,32), 256, 0, stream>>>(unmaskA, Wepe, nullptr, pee, tokcat + 10240, enc, 4096, 512, 768);
  // kv = enc @ [Wk;Wv]^T + [bk;bv]          (M=4096,N=1024,K=512)
  gemm_k<0><<<dim3(8,32), 256, 0, stream>>>(enc, inw_b + (size_t)512*512, inB + 512, nullptr, nullptr, kvb, 4096, 1024, 512);
  attn_k<<<512, 256, 0, stream>>>(qb, kvb, attnout);
  // pred = attn_raw @ Whp^T + bh  -> bf16   (M=10240,N=768,K=512)
  gemm_k<0><<<dim3(6,80), 256, 0, stream>>>(attnout, Whp, bh32, nullptr, nullptr, predb, 10240, 768, 512);

  finalize_k<<<9408, 256, 0, stream>>>(x, slot, predb, noise, out, partial);
  mse_reduce<<<1, 256, 0, stream>>>(partial, out);
}

// Round 5
// 229.725 us; speedup vs baseline: 9.3610x; 1.1015x over previous
//
#include <hip/hip_runtime.h>
#include <math.h>

typedef __attribute__((ext_vector_type(8))) __bf16 bf16x8;
typedef __attribute__((ext_vector_type(8))) unsigned short u16x8;
typedef __attribute__((ext_vector_type(4))) float f32x4;

typedef unsigned int as1_u32 __attribute__((address_space(1)));
typedef unsigned int as3_u32 __attribute__((address_space(3)));

// ---------- helpers ----------
__device__ __forceinline__ float bf2f(unsigned short h){
  return __uint_as_float(((unsigned int)h) << 16);
}
__device__ __forceinline__ unsigned short f2bf(float f){
  unsigned int u = __float_as_uint(f);
  unsigned int r = (u + 0x7FFFu + ((u >> 16) & 1u)) >> 16;  // RNE
  return (unsigned short)r;
}

#if __has_builtin(__builtin_amdgcn_global_load_lds)
#define HAVE_GLOAD_LDS 1
__device__ __forceinline__ void gload16(const void* g, void* l){
  __builtin_amdgcn_global_load_lds((const as1_u32*)(unsigned long long)g,
                                   (as3_u32*)l, 16, 0, 0);
}
#else
#define HAVE_GLOAD_LDS 0
#endif

// ---------- prep_all: scatter | transpose(WpeT,outwT) | conv(wcat) | pe2b+bh32 ----------
__global__ __launch_bounds__(256) void prep_all(
    const int* __restrict__ shuf, int* __restrict__ slot,
    const float* __restrict__ Wpe, const float* __restrict__ outw,
    unsigned short* __restrict__ WpeT, unsigned short* __restrict__ outwT,
    const float* __restrict__ encW, const float* __restrict__ inW,
    const float* __restrict__ headW, unsigned short* __restrict__ wcat,
    const float* __restrict__ pos, const float* __restrict__ b_pe,
    const float* __restrict__ outb, const float* __restrict__ headb,
    unsigned short* __restrict__ pe2b, float* __restrict__ bh32)
{
  const int bid = blockIdx.x, t = threadIdx.x;
  if (bid < 37){                                   // scatter_slots (slot pre-memset to -1)
    const int i = bid*256 + t;
    if (i < 64*147){
      const int b = i / 147, j = i % 147;
      slot[b*196 + shuf[b*196 + j]] = j;
    }
  } else if (bid < 677){                           // transpose W_pe -> WpeT, out_w -> outwT
    int b2 = bid - 37;
    const float* src; unsigned short* dst; int R, C, bx, by;
    if (b2 < 384){ src = Wpe;  dst = WpeT;  R = 512; C = 768; bx = b2 % 24; by = b2 / 24; }
    else { b2 -= 384; src = outw; dst = outwT; R = 512; C = 512; bx = b2 % 16; by = b2 / 16; }
    __shared__ float tile[32][33];
    const int tx = t & 31, ty = t >> 5;
    #pragma unroll
    for (int i = 0; i < 4; i++)
      tile[ty + i*8][tx] = src[(size_t)(by*32 + ty + i*8)*C + bx*32 + tx];
    __syncthreads();
    #pragma unroll
    for (int i = 0; i < 4; i++)
      dst[(size_t)(bx*32 + ty + i*8)*R + by*32 + tx] = f2bf(tile[tx][ty + i*8]);
  } else if (bid < 6309){                          // conv: encW|inW|headW -> bf16 wcat
    const int i = (bid - 677)*256 + t;             // < 1441792
    float v;
    if      (i <  262144) v = encW[i];
    else if (i < 1048576) v = inW[i -  262144];
    else                  v = headW[i - 1048576];
    wcat[i] = f2bf(v);
  } else {                                         // pe2b + bh32
    const int local = bid - 6309;
    if (local < 392){
      const int i = local*256 + t;                 // < 100352
      pe2b[i] = f2bf(pos[i] + b_pe[i & 511]);
    } else {
      const int r = (local - 392)*64 + (t >> 2);   // 0..767
      const int q4 = t & 3;
      float a = 0.0f;
      const float* hw = headW + (size_t)r*512 + q4*128;
      const float* ob = outb + q4*128;
      for (int e = 0; e < 128; e++) a += hw[e] * ob[e];
      a += __shfl_down(a, 2, 4);
      a += __shfl_down(a, 1, 4);
      if (q4 == 0) bh32[r] = a + headb[r];
    }
  }
}

// ---------- patchify: float4 loads -> LDS repack -> 16B bf16 stores ----------
__global__ __launch_bounds__(256) void patchify(const float* __restrict__ x, const int* __restrict__ shuf,
                         unsigned short* __restrict__ maskA, unsigned short* __restrict__ unmaskA,
                         int* __restrict__ tokcat)
{
  const int blk = blockIdx.x;
  const int b = blk / 224, ip = blk % 224;
  unsigned short* dst;
  int p = 0, valid;
  if (ip < 160){
    valid = (ip < 147);
    if (valid) p = shuf[b*196 + ip];
    dst = maskA + (size_t)(b*160 + ip) * 768;
    if (threadIdx.x == 0) tokcat[b*160 + ip] = p;
  } else {
    const int u = ip - 160;
    valid = (u < 49);
    if (valid) p = shuf[b*196 + 147 + u];
    dst = unmaskA + (size_t)(b*64 + u) * 768;
    if (threadIdx.x == 0) tokcat[10240 + b*64 + u] = p;
  }
  const int gh = p / 14, gw = p % 14;
  __shared__ float ld[768];
  const int t = threadIdx.x;
  if (valid && t < 192){
    const int seg = t >> 2, part = t & 3;
    const int c = seg >> 4, phi = seg & 15;
    const float4 v4 = *(const float4*)(x + (size_t)b*150528 + c*50176
                                       + (size_t)(gh*16 + phi)*224 + gw*16 + part*4);
    const int dbase = phi*48 + part*12 + c;
    ld[dbase]     = v4.x;
    ld[dbase + 3] = v4.y;
    ld[dbase + 6] = v4.z;
    ld[dbase + 9] = v4.w;
  }
  __syncthreads();
  if (t < 96){
    u16x8 o;
    if (valid){
      #pragma unroll
      for (int j = 0; j < 8; j++) o[j] = f2bf(ld[t*8 + j]);
    } else {
      #pragma unroll
      for (int j = 0; j < 8; j++) o[j] = 0;
    }
    *(u16x8*)&dst[t*8] = o;
  }
}

// ---------- unified descriptor GEMM: C[M,N] = A[M,K] @ W[N,K]^T (+epilogue) ----------
// tile 128x64, 4 waves (2x2; wave sub-tile 64x32), BK=32, double-buffered LDS,
// prefetch-next-before-compute, ONE barrier per K-step (T3-minimum pipeline).
// mode 0: +aux[col] -> bf16. 1: +aux[tok[row]*512+col] -> bf16. 2: mode1+gelu.
// mode 3: +aux[col] -> f32.  4: plain -> bf16.
struct GD {
  const unsigned short* A; const unsigned short* W; const float* aux;
  const int* tok; unsigned short* ob; float* of;
  int N, K, mode, blk0, nx;
};

__global__ __launch_bounds__(256) void gemm2(GD g0, GD g1, GD g2, GD g3, GD g4){
  const int bid = blockIdx.x;
  GD g = g0;
  if (bid >= g1.blk0) g = g1;
  if (bid >= g2.blk0) g = g2;
  if (bid >= g3.blk0) g = g3;
  if (bid >= g4.blk0) g = g4;
  const int local = bid - g.blk0;
  const int tn = (local % g.nx) * 64;
  const int tm = (local / g.nx) * 128;
  const int N = g.N, K = g.K;

  __shared__ unsigned short As[2*128*32];
  __shared__ unsigned short Bs[2*64*32];
  const int t = threadIdx.x;
  const int wave = t >> 6, lane = t & 63;
  const int wr = (wave >> 1) * 64, wc = (wave & 1) * 32;
  const int lr = lane & 15, lg = lane >> 4;

  f32x4 acc[4][2] = {};

#if HAVE_GLOAD_LDS
  const int srow = lane >> 2;          // 0..15
  const int scol = (lane & 3) * 8;     // k-offset within BK=32
  const unsigned short* Ag = g.A + (size_t)(tm + wave*32 + srow) * K + scol;
  const unsigned short* Bg = g.W + (size_t)(tn + wave*16 + srow) * K + scol;
  unsigned short* Al0 = As + wave*(32*32);
  unsigned short* Bl0 = Bs + wave*(16*32);
  const size_t rstepA = (size_t)16 * K;

  // prologue: stage tile 0 into buf 0
  gload16(Ag,          Al0);
  gload16(Ag + rstepA, Al0 + 16*32);
  gload16(Bg,          Bl0);
  __syncthreads();

  const int nt = K >> 5;
  for (int tt = 0; tt < nt; ++tt){
    const int cur = tt & 1;
    if (tt + 1 < nt){                 // prefetch next tile into other buffer
      const int k0 = (tt + 1) * 32;
      unsigned short* Al = Al0 + (cur^1)*(128*32);
      unsigned short* Bl = Bl0 + (cur^1)*(64*32);
      gload16(Ag + k0,          Al);
      gload16(Ag + k0 + rstepA, Al + 16*32);
      gload16(Bg + k0,          Bl);
    }
    const unsigned short* Ab = As + cur*(128*32);
    const unsigned short* Bb = Bs + cur*(64*32);
    bf16x8 av[4], bv[2];
    #pragma unroll
    for (int mi = 0; mi < 4; mi++) av[mi] = *(const bf16x8*)&Ab[(wr + mi*16 + lr)*32 + lg*8];
    #pragma unroll
    for (int ni = 0; ni < 2; ni++) bv[ni] = *(const bf16x8*)&Bb[(wc + ni*16 + lr)*32 + lg*8];
    #pragma unroll
    for (int mi = 0; mi < 4; mi++)
      #pragma unroll
      for (int ni = 0; ni < 2; ni++)
        acc[mi][ni] = __builtin_amdgcn_mfma_f32_16x16x32_bf16(av[mi], bv[ni], acc[mi][ni], 0, 0, 0);
    __syncthreads();   // drains vmcnt(0): prefetched tile resident; LDS reads done
  }
#else
  const int r0 = t >> 2;
  const int c0 = (t & 3) * 8;
  for (int k0 = 0; k0 < K; k0 += 32){
    u16x8 ra0 = *(const u16x8*)(g.A + (size_t)(tm + r0) * K + k0 + c0);
    u16x8 rb0 = (r0 < 64) ? *(const u16x8*)(g.W + (size_t)(tn + r0) * K + k0 + c0) : u16x8{};
    __syncthreads();
    *(u16x8*)&As[r0 * 32 + c0] = ra0;
    if (r0 < 64) *(u16x8*)&Bs[r0 * 32 + c0] = rb0;
    __syncthreads();
    bf16x8 av[4], bv[2];
    #pragma unroll
    for (int mi = 0; mi < 4; mi++) av[mi] = *(const bf16x8*)&As[(wr + mi*16 + lr)*32 + lg*8];
    #pragma unroll
    for (int ni = 0; ni < 2; ni++) bv[ni] = *(const bf16x8*)&Bs[(wc + ni*16 + lr)*32 + lg*8];
    #pragma unroll
    for (int mi = 0; mi < 4; mi++)
      #pragma unroll
      for (int ni = 0; ni < 2; ni++)
        acc[mi][ni] = __builtin_amdgcn_mfma_f32_16x16x32_bf16(av[mi], bv[ni], acc[mi][ni], 0, 0, 0);
  }
#endif

  // epilogue: C/D layout col=lane&15, row=(lane>>4)*4+jj
  const int mode = g.mode;
  #pragma unroll
  for (int ni = 0; ni < 2; ni++){
    const int gcol = tn + wc + ni*16 + lr;
    const float bval = (mode == 0 || mode == 3) ? g.aux[gcol] : 0.0f;
    #pragma unroll
    for (int mi = 0; mi < 4; mi++){
      #pragma unroll
      for (int jj = 0; jj < 4; jj++){
        const int grow = tm + wr + mi*16 + lg*4 + jj;
        float v = acc[mi][ni][jj] + bval;
        if (mode == 1 || mode == 2) v += g.aux[(size_t)g.tok[grow] * 512 + gcol];
        if (mode == 2){
          const float u = v;
          v = 0.5f * u * (1.0f + tanhf(0.7978845608f * (u + 0.044715f * u * u * u)));
        }
        if (mode == 3) g.of[(size_t)grow * N + gcol] = v;
        else           g.ob[(size_t)grow * N + gcol] = f2bf(v);
      }
    }
  }
}

// ---------- attention: block per (b,h); q 147x64, k/v 49x64 ----------
__global__ __launch_bounds__(256) void attn_k(const unsigned short* __restrict__ qb,
                                              const unsigned short* __restrict__ kv,
                                              unsigned short* __restrict__ attnout)
{
  const int b = blockIdx.x >> 3, h = blockIdx.x & 7;
  __shared__ float ks[49][64];
  __shared__ float vs[49][64];
  __shared__ float pwt[147][49];
  __shared__ float inv_[147];
  const int t = threadIdx.x;
  for (int idx = t; idx < 49*64; idx += 256){
    const int j = idx >> 6, d = idx & 63;
    const size_t base = (size_t)(b*64 + j)*1024 + h*64 + d;
    ks[j][d] = bf2f(kv[base]);
    vs[j][d] = bf2f(kv[base + 512]);
  }
  __syncthreads();
  if (t < 147){
    float qv[64];
    const unsigned short* qp = qb + (size_t)(b*160 + t)*512 + h*64;
    #pragma unroll
    for (int d = 0; d < 64; d++) qv[d] = bf2f(qp[d]);
    for (int j = 0; j < 49; j++){
      float s = 0.0f;
      #pragma unroll
      for (int d = 0; d < 64; d++) s += qv[d] * ks[j][d];
      pwt[t][j] = s * 0.125f;
    }
    float m = -1e30f;
    for (int j = 0; j < 49; j++) m = fmaxf(m, pwt[t][j]);
    float sum = 0.0f;
    for (int j = 0; j < 49; j++){ const float e = __expf(pwt[t][j] - m); pwt[t][j] = e; sum += e; }
    inv_[t] = 1.0f / sum;
  }
  __syncthreads();
  for (int idx = t; idx < 147*64; idx += 256){
    const int i = idx >> 6, d = idx & 63;
    float s = 0.0f;
    for (int j = 0; j < 49; j++) s += pwt[i][j] * vs[j][d];
    s *= inv_[i];
    attnout[(size_t)(b*160 + i)*512 + h*64 + d] = f2bf(s);
  }
}

// ---------- final: three images + per-block |err| partials; 4 pixels/thread ----------
__global__ __launch_bounds__(256) void finalize_k(const float* __restrict__ x, const int* __restrict__ slot,
                           const unsigned short* __restrict__ predb, const float* __restrict__ noise,
                           float* __restrict__ out, float* __restrict__ partial)
{
  const int i4 = blockIdx.x * 256 + threadIdx.x;
  const int idx = i4 * 4;
  const int w = idx % 224;
  const int h = (idx / 224) % 224;
  const int c = (idx / 50176) % 3;
  const int b = idx / 150528;
  const float4 xv = *(const float4*)(x + idx);
  const int p = (h >> 4) * 14 + (w >> 4);
  const int s = slot[b*196 + p];
  float4 rec = xv, noi = xv, mim = xv;
  float a = 0.0f;
  if (s >= 0){
    const int d = (h & 15)*48 + (w & 15)*3 + c;
    const size_t pb = (size_t)(b*160 + s)*768 + d;
    const size_t nb = (size_t)(b*147 + s)*768 + d;
    rec = make_float4(bf2f(predb[pb]), bf2f(predb[pb+3]), bf2f(predb[pb+6]), bf2f(predb[pb+9]));
    noi = make_float4(noise[nb], noise[nb+3], noise[nb+6], noise[nb+9]);
    mim = make_float4(1.0f, 1.0f, 1.0f, 1.0f);
    a = fabsf(rec.x - xv.x) + fabsf(rec.y - xv.y) + fabsf(rec.z - xv.z) + fabsf(rec.w - xv.w);
  }
  *(float4*)(out + idx) = rec;
  *(float4*)(out + 9633792 + idx) = noi;
  float* m3 = out + 19267585 + idx;
  m3[0] = mim.x; m3[1] = mim.y; m3[2] = mim.z; m3[3] = mim.w;
  #pragma unroll
  for (int o = 32; o > 0; o >>= 1) a += __shfl_down(a, o);
  __shared__ float wsum[4];
  if ((threadIdx.x & 63) == 0) wsum[threadIdx.x >> 6] = a;
  __syncthreads();
  if (threadIdx.x == 0)
    partial[blockIdx.x] = wsum[0] + wsum[1] + wsum[2] + wsum[3];
}

__global__ __launch_bounds__(256) void mse_reduce(const float* __restrict__ partial, float* __restrict__ out){
  float a = 0.0f;
  for (int i = threadIdx.x; i < 9408; i += 256) a += partial[i];
  #pragma unroll
  for (int o = 32; o > 0; o >>= 1) a += __shfl_down(a, o);
  __shared__ float wsum[4];
  if ((threadIdx.x & 63) == 0) wsum[threadIdx.x >> 6] = a;
  __syncthreads();
  if (threadIdx.x == 0)
    out[19267584] = (wsum[0] + wsum[1] + wsum[2] + wsum[3]) * (1.0f / 7225344.0f);
}

// ---------- launch ----------
extern "C" void kernel_launch(void* const* d_in, const int* in_sizes, int n_in,
                              void* d_out, int out_size, void* d_ws, size_t ws_size,
                              hipStream_t stream)
{
  const float* x     = (const float*)d_in[0];
  const int*   shuf  = (const int*)d_in[1];
  const float* W_pe  = (const float*)d_in[2];
  const float* b_pe  = (const float*)d_in[3];
  const float* pos   = (const float*)d_in[4];
  const float* encW  = (const float*)d_in[5];
  const float* encB  = (const float*)d_in[6];
  const float* inW   = (const float*)d_in[7];
  const float* inB   = (const float*)d_in[8];
  const float* outW  = (const float*)d_in[9];
  const float* outB  = (const float*)d_in[10];
  const float* headW = (const float*)d_in[11];
  const float* headB = (const float*)d_in[12];
  const float* noise = (const float*)d_in[13];
  float* out = (float*)d_out;

  char* ws = (char*)d_ws;
  size_t cur = 0;
  auto alloc = [&](size_t bytes){ size_t o = cur; cur += (bytes + 255) & ~(size_t)255; return o; };

  int*   slot    = (int*)(ws + alloc(64*196*4));
  int*   tokcat  = (int*)(ws + alloc(14336*4));
  float* partial = (float*)(ws + alloc(9408*4));
  unsigned short* wcat    = (unsigned short*)(ws + alloc((size_t)1441792*2));
  unsigned short* encw_b  = wcat;
  unsigned short* inw_b   = wcat +  262144;   // [Wq;Wk;Wv]
  unsigned short* headw_b = wcat + 1048576;   // [768][512]
  unsigned short* WpeT  = (unsigned short*)(ws + alloc((size_t)393216*2));  // [768][512]
  unsigned short* outwT = (unsigned short*)(ws + alloc((size_t)262144*2));  // [512][512]
  unsigned short* Wqpe  = (unsigned short*)(ws + alloc((size_t)393216*2));  // [512][768]
  unsigned short* Wepe  = (unsigned short*)(ws + alloc((size_t)393216*2));  // [512][768]
  unsigned short* Whp   = (unsigned short*)(ws + alloc((size_t)393216*2));  // [768][512]
  unsigned short* pe2b  = (unsigned short*)(ws + alloc((size_t)131072*2));  // [256][512]
  float* peq  = (float*)(ws + alloc((size_t)131072*4));
  float* pee  = (float*)(ws + alloc((size_t)131072*4));
  float* bh32 = (float*)(ws + alloc(768*4));
  char* R0 = ws + alloc(26214400);
  unsigned short* maskA   = (unsigned short*)R0;
  unsigned short* unmaskA = (unsigned short*)(R0 + 15728640);
  unsigned short* attnout = (unsigned short*)R0;                 // alive attn..pred (maskA dead)
  unsigned short* predb   = (unsigned short*)(R0 + 10485760);    // alive pred..finalize
  unsigned short* enc   = (unsigned short*)(ws + alloc((size_t)2097152*2));
  unsigned short* qb    = (unsigned short*)(ws + alloc((size_t)5242880*2));
  unsigned short* kvb   = (unsigned short*)(ws + alloc((size_t)4194304*2));

  const int BIG = 0x7FFFFFFF;

  hipMemsetAsync(slot, 0xFF, 64*196*4, stream);    // slot = -1
  prep_all<<<6713, 256, 0, stream>>>(shuf, slot, W_pe, outW, WpeT, outwT,
                                     encW, inW, headW, wcat,
                                     pos, b_pe, outB, headB, pe2b, bh32);
  patchify<<<64*224, 256, 0, stream>>>(x, shuf, maskA, unmaskA, tokcat);

  // fold GEMMs (one launch, 176 blocks):
  // t1 Wqpe = Wq @ WpeT'      (512x768,K=512)  t2 Wepe = encW @ WpeT'  (512x768)
  // t3 Whp  = headW @ outwT'  (768x512)        t4 peq  = pe2b @ Wq' +bq (256x512, f32)
  // t5 pee  = pe2b @ encW' +encb (256x512, f32)
  {
    GD t1 = { inw_b,  WpeT,   nullptr, nullptr, Wqpe,   nullptr, 768, 512, 4,   0, 12 };
    GD t2 = { encw_b, WpeT,   nullptr, nullptr, Wepe,   nullptr, 768, 512, 4,  48, 12 };
    GD t3 = { headw_b,outwT,  nullptr, nullptr, Whp,    nullptr, 512, 512, 4,  96,  8 };
    GD t4 = { pe2b,   inw_b,  inB,     nullptr, nullptr, peq,    512, 512, 3, 144,  8 };
    GD t5 = { pe2b,   encw_b, encB,    nullptr, nullptr, pee,    512, 512, 3, 160,  8 };
    gemm2<<<176, 256, 0, stream>>>(t1, t2, t3, t4, t5);
  }
  // q + enc (independent; one launch, 896 blocks):
  {
    GD q  = { maskA,   Wqpe, peq, tokcat,         qb,  nullptr, 512, 768, 1,   0, 8 };
    GD en = { unmaskA, Wepe, pee, tokcat + 10240, enc, nullptr, 512, 768, 2, 640, 8 };
    GD nz = q; nz.blk0 = BIG;
    gemm2<<<896, 256, 0, stream>>>(q, en, nz, nz, nz);
  }
  // kv = enc @ [Wk;Wv]^T + [bk;bv]  (4096x1024,K=512; 512 blocks)
  {
    GD kv = { enc, inw_b + (size_t)512*512, inB + 512, nullptr, kvb, nullptr, 1024, 512, 0, 0, 16 };
    GD nz = kv; nz.blk0 = BIG;
    gemm2<<<512, 256, 0, stream>>>(kv, nz, nz, nz, nz);
  }
  attn_k<<<512, 256, 0, stream>>>(qb, kvb, attnout);
  // pred = attn_raw @ Whp^T + bh  (10240x768,K=512; 960 blocks)
  {
    GD pr = { attnout, Whp, bh32, nullptr, predb, nullptr, 768, 512, 0, 0, 12 };
    GD nz = pr; nz.blk0 = BIG;
    gemm2<<<960, 256, 0, stream>>>(pr, nz, nz, nz, nz);
  }

  finalize_k<<<9408, 256, 0, stream>>>(x, slot, predb, noise, out, partial);
  mse_reduce<<<1, 256, 0, stream>>>(partial, out);
}

// Round 6
// 183.141 us; speedup vs baseline: 11.7421x; 1.2544x over previous
//
#include <hip/hip_runtime.h>
#include <math.h>

typedef __attribute__((ext_vector_type(8))) __bf16 bf16x8;
typedef __attribute__((ext_vector_type(8))) unsigned short u16x8;
typedef __attribute__((ext_vector_type(4))) float f32x4;

typedef unsigned int as1_u32 __attribute__((address_space(1)));
typedef unsigned int as3_u32 __attribute__((address_space(3)));

// ---------- helpers ----------
__device__ __forceinline__ float bf2f(unsigned short h){
  return __uint_as_float(((unsigned int)h) << 16);
}
__device__ __forceinline__ unsigned short f2bf(float f){
  unsigned int u = __float_as_uint(f);
  unsigned int r = (u + 0x7FFFu + ((u >> 16) & 1u)) >> 16;  // RNE
  return (unsigned short)r;
}

#if __has_builtin(__builtin_amdgcn_global_load_lds)
#define HAVE_GLOAD_LDS 1
__device__ __forceinline__ void gload16(const void* g, void* l){
  __builtin_amdgcn_global_load_lds((const as1_u32*)(unsigned long long)g,
                                   (as3_u32*)l, 16, 0, 0);
}
#else
#define HAVE_GLOAD_LDS 0
#endif

// ---------- prep_all: scatter | transpose | conv | pe2b+bh32 | patchify ----------
// block ranges: [0,49) scatter  [49,689) transpose  [689,6321) conv
//               [6321,6713) pe2b  [6713,6725) bh32  [6725,21061) patchify
__global__ __launch_bounds__(256) void prep_all(
    const int* __restrict__ shuf, int* __restrict__ slot,
    const float* __restrict__ Wpe, const float* __restrict__ outw,
    unsigned short* __restrict__ WpeT, unsigned short* __restrict__ outwT,
    const float* __restrict__ encW, const float* __restrict__ inW,
    const float* __restrict__ headW, unsigned short* __restrict__ wcat,
    const float* __restrict__ pos, const float* __restrict__ b_pe,
    const float* __restrict__ outb, const float* __restrict__ headb,
    unsigned short* __restrict__ pe2b, float* __restrict__ bh32,
    const float* __restrict__ x,
    unsigned short* __restrict__ maskA, unsigned short* __restrict__ unmaskA,
    int* __restrict__ tokcat)
{
  const int bid = blockIdx.x, t = threadIdx.x;
  __shared__ float tile[32][33];   // transpose
  __shared__ float ld[768];        // patchify
  if (bid < 49){                                   // scatter covers ALL 196 (permutation)
    const int i = bid*256 + t;
    if (i < 64*196){
      const int b = i / 196, j = i % 196;
      slot[b*196 + shuf[b*196 + j]] = (j < 147) ? j : -1;
    }
  } else if (bid < 689){                           // transpose W_pe -> WpeT, out_w -> outwT
    int b2 = bid - 49;
    const float* src; unsigned short* dst; int R, C, bx, by;
    if (b2 < 384){ src = Wpe;  dst = WpeT;  R = 512; C = 768; bx = b2 % 24; by = b2 / 24; }
    else { b2 -= 384; src = outw; dst = outwT; R = 512; C = 512; bx = b2 % 16; by = b2 / 16; }
    const int tx = t & 31, ty = t >> 5;
    #pragma unroll
    for (int i = 0; i < 4; i++)
      tile[ty + i*8][tx] = src[(size_t)(by*32 + ty + i*8)*C + bx*32 + tx];
    __syncthreads();
    #pragma unroll
    for (int i = 0; i < 4; i++)
      dst[(size_t)(bx*32 + ty + i*8)*R + by*32 + tx] = f2bf(tile[tx][ty + i*8]);
  } else if (bid < 6321){                          // conv: encW|inW|headW -> bf16 wcat
    const int i = (bid - 689)*256 + t;             // < 1441792
    float v;
    if      (i <  262144) v = encW[i];
    else if (i < 1048576) v = inW[i -  262144];
    else                  v = headW[i - 1048576];
    wcat[i] = f2bf(v);
  } else if (bid < 6713){                          // pe2b
    const int i = (bid - 6321)*256 + t;            // < 100352
    pe2b[i] = f2bf(pos[i] + b_pe[i & 511]);
  } else if (bid < 6725){                          // bh32 = headW@outb + headb
    const int r = (bid - 6713)*64 + (t >> 2);      // 0..767
    const int q4 = t & 3;
    float a = 0.0f;
    const float* hw = headW + (size_t)r*512 + q4*128;
    const float* ob = outb + q4*128;
    for (int e = 0; e < 128; e++) a += hw[e] * ob[e];
    a += __shfl_down(a, 2, 4);
    a += __shfl_down(a, 1, 4);
    if (q4 == 0) bh32[r] = a + headb[r];
  } else {                                         // patchify
    const int blk = bid - 6725;
    const int b = blk / 224, ip = blk % 224;
    unsigned short* dst;
    int p = 0, valid;
    if (ip < 160){
      valid = (ip < 147);
      if (valid) p = shuf[b*196 + ip];
      dst = maskA + (size_t)(b*160 + ip) * 768;
      if (t == 0) tokcat[b*160 + ip] = p;
    } else {
      const int u = ip - 160;
      valid = (u < 49);
      if (valid) p = shuf[b*196 + 147 + u];
      dst = unmaskA + (size_t)(b*64 + u) * 768;
      if (t == 0) tokcat[10240 + b*64 + u] = p;
    }
    const int gh = p / 14, gw = p % 14;
    if (valid && t < 192){
      const int seg = t >> 2, part = t & 3;
      const int c = seg >> 4, phi = seg & 15;
      const float4 v4 = *(const float4*)(x + (size_t)b*150528 + c*50176
                                         + (size_t)(gh*16 + phi)*224 + gw*16 + part*4);
      const int dbase = phi*48 + part*12 + c;
      ld[dbase]     = v4.x;
      ld[dbase + 3] = v4.y;
      ld[dbase + 6] = v4.z;
      ld[dbase + 9] = v4.w;
    }
    __syncthreads();
    if (t < 96){
      u16x8 o;
      if (valid){
        #pragma unroll
        for (int j = 0; j < 8; j++) o[j] = f2bf(ld[t*8 + j]);
      } else {
        #pragma unroll
        for (int j = 0; j < 8; j++) o[j] = 0;
      }
      *(u16x8*)&dst[t*8] = o;
    }
  }
}

// ---------- unified descriptor GEMM (unchanged structure from R4) ----------
struct GD {
  const unsigned short* A; const unsigned short* W; const float* aux;
  const int* tok; unsigned short* ob; float* of;
  int N, K, mode, blk0, nx;
};

__global__ __launch_bounds__(256) void gemm2(GD g0, GD g1, GD g2, GD g3, GD g4){
  const int bid = blockIdx.x;
  GD g = g0;
  if (bid >= g1.blk0) g = g1;
  if (bid >= g2.blk0) g = g2;
  if (bid >= g3.blk0) g = g3;
  if (bid >= g4.blk0) g = g4;
  const int local = bid - g.blk0;
  const int tn = (local % g.nx) * 64;
  const int tm = (local / g.nx) * 128;
  const int N = g.N, K = g.K;

  __shared__ unsigned short As[2*128*32];
  __shared__ unsigned short Bs[2*64*32];
  const int t = threadIdx.x;
  const int wave = t >> 6, lane = t & 63;
  const int wr = (wave >> 1) * 64, wc = (wave & 1) * 32;
  const int lr = lane & 15, lg = lane >> 4;

  f32x4 acc[4][2] = {};

#if HAVE_GLOAD_LDS
  const int srow = lane >> 2;
  const int scol = (lane & 3) * 8;
  const unsigned short* Ag = g.A + (size_t)(tm + wave*32 + srow) * K + scol;
  const unsigned short* Bg = g.W + (size_t)(tn + wave*16 + srow) * K + scol;
  unsigned short* Al0 = As + wave*(32*32);
  unsigned short* Bl0 = Bs + wave*(16*32);
  const size_t rstepA = (size_t)16 * K;

  gload16(Ag,          Al0);
  gload16(Ag + rstepA, Al0 + 16*32);
  gload16(Bg,          Bl0);
  __syncthreads();

  const int nt = K >> 5;
  for (int tt = 0; tt < nt; ++tt){
    const int cur = tt & 1;
    if (tt + 1 < nt){
      const int k0 = (tt + 1) * 32;
      unsigned short* Al = Al0 + (cur^1)*(128*32);
      unsigned short* Bl = Bl0 + (cur^1)*(64*32);
      gload16(Ag + k0,          Al);
      gload16(Ag + k0 + rstepA, Al + 16*32);
      gload16(Bg + k0,          Bl);
    }
    const unsigned short* Ab = As + cur*(128*32);
    const unsigned short* Bb = Bs + cur*(64*32);
    bf16x8 av[4], bv[2];
    #pragma unroll
    for (int mi = 0; mi < 4; mi++) av[mi] = *(const bf16x8*)&Ab[(wr + mi*16 + lr)*32 + lg*8];
    #pragma unroll
    for (int ni = 0; ni < 2; ni++) bv[ni] = *(const bf16x8*)&Bb[(wc + ni*16 + lr)*32 + lg*8];
    #pragma unroll
    for (int mi = 0; mi < 4; mi++)
      #pragma unroll
      for (int ni = 0; ni < 2; ni++)
        acc[mi][ni] = __builtin_amdgcn_mfma_f32_16x16x32_bf16(av[mi], bv[ni], acc[mi][ni], 0, 0, 0);
    __syncthreads();
  }
#else
  const int r0 = t >> 2;
  const int c0 = (t & 3) * 8;
  for (int k0 = 0; k0 < K; k0 += 32){
    u16x8 ra0 = *(const u16x8*)(g.A + (size_t)(tm + r0) * K + k0 + c0);
    u16x8 rb0 = (r0 < 64) ? *(const u16x8*)(g.W + (size_t)(tn + r0) * K + k0 + c0) : u16x8{};
    __syncthreads();
    *(u16x8*)&As[r0 * 32 + c0] = ra0;
    if (r0 < 64) *(u16x8*)&Bs[r0 * 32 + c0] = rb0;
    __syncthreads();
    bf16x8 av[4], bv[2];
    #pragma unroll
    for (int mi = 0; mi < 4; mi++) av[mi] = *(const bf16x8*)&As[(wr + mi*16 + lr)*32 + lg*8];
    #pragma unroll
    for (int ni = 0; ni < 2; ni++) bv[ni] = *(const bf16x8*)&Bs[(wc + ni*16 + lr)*32 + lg*8];
    #pragma unroll
    for (int mi = 0; mi < 4; mi++)
      #pragma unroll
      for (int ni = 0; ni < 2; ni++)
        acc[mi][ni] = __builtin_amdgcn_mfma_f32_16x16x32_bf16(av[mi], bv[ni], acc[mi][ni], 0, 0, 0);
  }
#endif

  const int mode = g.mode;
  #pragma unroll
  for (int ni = 0; ni < 2; ni++){
    const int gcol = tn + wc + ni*16 + lr;
    const float bval = (mode == 0 || mode == 3) ? g.aux[gcol] : 0.0f;
    #pragma unroll
    for (int mi = 0; mi < 4; mi++){
      #pragma unroll
      for (int jj = 0; jj < 4; jj++){
        const int grow = tm + wr + mi*16 + lg*4 + jj;
        float v = acc[mi][ni][jj] + bval;
        if (mode == 1 || mode == 2) v += g.aux[(size_t)g.tok[grow] * 512 + gcol];
        if (mode == 2){
          const float u = v;
          v = 0.5f * u * (1.0f + tanhf(0.7978845608f * (u + 0.044715f * u * u * u)));
        }
        if (mode == 3) g.of[(size_t)grow * N + gcol] = v;
        else           g.ob[(size_t)grow * N + gcol] = f2bf(v);
      }
    }
  }
}

// ---------- MFMA attention: block per (b,h) ----------
// qs[192][72] bf16 (rows>=160 zero), ks[64][72], vsT[64][72] (v transposed),
// pwt[192][66] f32 scores, pa[192][72] bf16 probs (rows>=147 and cols>=49 zero).
__global__ __launch_bounds__(256) void attn_mfma(const unsigned short* __restrict__ qb,
                                                 const unsigned short* __restrict__ kv,
                                                 unsigned short* __restrict__ attnout)
{
  const int b = blockIdx.x >> 3, h = blockIdx.x & 7;
  __shared__ unsigned short qs[192*72];
  __shared__ unsigned short ks[64*72];
  __shared__ unsigned short vsT[64*72];
  __shared__ float pwt[192*66];
  __shared__ unsigned short pa[192*72];
  __shared__ float inv_[160];
  const int t = threadIdx.x;
  const int wave = t >> 6, lane = t & 63;
  const int wr = (wave >> 1) * 96, wc = (wave & 1) * 32;
  const int lr = lane & 15, lg = lane >> 4;

  // stage q (zero-pad rows >=160)
  for (int idx = t; idx < 192*8; idx += 256){
    const int i = idx >> 3, g = idx & 7;
    u16x8 v = {};
    if (i < 160) v = *(const u16x8*)(qb + (size_t)(b*160 + i)*512 + h*64 + g*8);
    *(u16x8*)&qs[i*72 + g*8] = v;
  }
  // stage k + v^T
  for (int idx = t; idx < 64*8; idx += 256){
    const int j = idx >> 3, g = idx & 7;
    const size_t base = (size_t)(b*64 + j)*1024 + h*64 + g*8;
    u16x8 k8 = *(const u16x8*)(kv + base);
    u16x8 v8 = *(const u16x8*)(kv + base + 512);
    *(u16x8*)&ks[j*72 + g*8] = k8;
    #pragma unroll
    for (int d = 0; d < 8; d++) vsT[(g*8 + d)*72 + j] = v8[d];
  }
  __syncthreads();

  // QK^T: scores[192][64] = qs @ ks^T, K=64
  {
    f32x4 acc[6][2] = {};
    #pragma unroll
    for (int ksv = 0; ksv < 2; ksv++){
      const int kk = ksv*32;
      bf16x8 av[6], bv[2];
      #pragma unroll
      for (int mi = 0; mi < 6; mi++) av[mi] = *(const bf16x8*)&qs[(wr + mi*16 + lr)*72 + kk + lg*8];
      #pragma unroll
      for (int ni = 0; ni < 2; ni++) bv[ni] = *(const bf16x8*)&ks[(wc + ni*16 + lr)*72 + kk + lg*8];
      #pragma unroll
      for (int mi = 0; mi < 6; mi++)
        #pragma unroll
        for (int ni = 0; ni < 2; ni++)
          acc[mi][ni] = __builtin_amdgcn_mfma_f32_16x16x32_bf16(av[mi], bv[ni], acc[mi][ni], 0, 0, 0);
    }
    #pragma unroll
    for (int mi = 0; mi < 6; mi++)
      #pragma unroll
      for (int ni = 0; ni < 2; ni++)
        #pragma unroll
        for (int jj = 0; jj < 4; jj++)
          pwt[(wr + mi*16 + lg*4 + jj)*66 + wc + ni*16 + lr] = acc[mi][ni][jj] * 0.125f;
  }
  __syncthreads();

  // softmax per row (mask j>=49); pa bf16
  if (t < 147){
    float m = -1e30f;
    for (int j = 0; j < 49; j++) m = fmaxf(m, pwt[t*66 + j]);
    float sum = 0.0f;
    for (int j = 0; j < 49; j++){
      const float e = __expf(pwt[t*66 + j] - m);
      sum += e;
      pa[t*72 + j] = f2bf(e);
    }
    inv_[t] = 1.0f / sum;
    for (int j = 49; j < 64; j++) pa[t*72 + j] = 0;
  } else if (t < 192){
    for (int j = 0; j < 64; j++) pa[t*72 + j] = 0;
    if (t < 160) inv_[t] = 0.0f;
  }
  __syncthreads();

  // PV: out[192][64] = pa @ vsT^T (K=64 over j)
  {
    f32x4 acc[6][2] = {};
    #pragma unroll
    for (int ksv = 0; ksv < 2; ksv++){
      const int kk = ksv*32;
      bf16x8 av[6], bv[2];
      #pragma unroll
      for (int mi = 0; mi < 6; mi++) av[mi] = *(const bf16x8*)&pa[(wr + mi*16 + lr)*72 + kk + lg*8];
      #pragma unroll
      for (int ni = 0; ni < 2; ni++) bv[ni] = *(const bf16x8*)&vsT[(wc + ni*16 + lr)*72 + kk + lg*8];
      #pragma unroll
      for (int mi = 0; mi < 6; mi++)
        #pragma unroll
        for (int ni = 0; ni < 2; ni++)
          acc[mi][ni] = __builtin_amdgcn_mfma_f32_16x16x32_bf16(av[mi], bv[ni], acc[mi][ni], 0, 0, 0);
    }
    #pragma unroll
    for (int mi = 0; mi < 6; mi++)
      #pragma unroll
      for (int ni = 0; ni < 2; ni++)
        #pragma unroll
        for (int jj = 0; jj < 4; jj++){
          const int grow = wr + mi*16 + lg*4 + jj;
          if (grow < 160){
            const float sc = inv_[grow];
            const float v = acc[mi][ni][jj] * sc;
            attnout[(size_t)(b*160 + grow)*512 + h*64 + wc + ni*16 + lr] = f2bf(v);
          }
        }
  }
}

// ---------- final: three images + per-block |err| partials; 4 pixels/thread ----------
__global__ __launch_bounds__(256) void finalize_k(const float* __restrict__ x, const int* __restrict__ slot,
                           const unsigned short* __restrict__ predb, const float* __restrict__ noise,
                           float* __restrict__ out, float* __restrict__ partial)
{
  const int i4 = blockIdx.x * 256 + threadIdx.x;
  const int idx = i4 * 4;
  const int w = idx % 224;
  const int h = (idx / 224) % 224;
  const int c = (idx / 50176) % 3;
  const int b = idx / 150528;
  const float4 xv = *(const float4*)(x + idx);
  const int p = (h >> 4) * 14 + (w >> 4);
  const int s = slot[b*196 + p];
  float4 rec = xv, noi = xv;
  float mimv = 0.0f;   // per-quad mim is uniform? no: mim = s>=0 ? 1 : x — per-pixel
  float a = 0.0f;
  float4 mim = xv;
  if (s >= 0){
    const int d = (h & 15)*48 + (w & 15)*3 + c;
    const size_t pb = (size_t)(b*160 + s)*768 + d;
    const size_t nb = (size_t)(b*147 + s)*768 + d;
    rec = make_float4(bf2f(predb[pb]), bf2f(predb[pb+3]), bf2f(predb[pb+6]), bf2f(predb[pb+9]));
    noi = make_float4(noise[nb], noise[nb+3], noise[nb+6], noise[nb+9]);
    mim = make_float4(1.0f, 1.0f, 1.0f, 1.0f);
    a = fabsf(rec.x - xv.x) + fabsf(rec.y - xv.y) + fabsf(rec.z - xv.z) + fabsf(rec.w - xv.w);
  }
  (void)mimv;
  *(float4*)(out + idx) = rec;
  *(float4*)(out + 9633792 + idx) = noi;
  // mask_image starts at odd offset 19267585: shifted aligned store
  // lane stores {mim[idx-1], mim[idx], mim[idx+1], mim[idx+2]} at 19267584+idx
  float prevm = __shfl_up(mim.w, 1);
  if ((threadIdx.x & 63) == 0 && idx > 0){
    const int pidx = idx - 1;
    const int pw2 = pidx % 224, ph2 = (pidx / 224) % 224;
    const int pb2 = pidx / 150528;
    const int pp = (ph2 >> 4) * 14 + (pw2 >> 4);
    prevm = (slot[pb2*196 + pp] >= 0) ? 1.0f : x[pidx];
  }
  *(float4*)(out + 19267584 + idx) = make_float4(prevm, mim.x, mim.y, mim.z);
  if (i4 == 2408447) out[28901376] = mim.w;   // tail pixel
  // block reduce -> partial
  #pragma unroll
  for (int o = 32; o > 0; o >>= 1) a += __shfl_down(a, o);
  __shared__ float wsum[4];
  if ((threadIdx.x & 63) == 0) wsum[threadIdx.x >> 6] = a;
  __syncthreads();
  if (threadIdx.x == 0)
    partial[blockIdx.x] = wsum[0] + wsum[1] + wsum[2] + wsum[3];
}

__global__ __launch_bounds__(1024) void mse_reduce(const float* __restrict__ partial, float* __restrict__ out){
  float a = 0.0f;
  for (int i = threadIdx.x; i < 9408; i += 1024) a += partial[i];
  #pragma unroll
  for (int o = 32; o > 0; o >>= 1) a += __shfl_down(a, o);
  __shared__ float wsum[16];
  if ((threadIdx.x & 63) == 0) wsum[threadIdx.x >> 6] = a;
  __syncthreads();
  if (threadIdx.x == 0){
    float s = 0.0f;
    #pragma unroll
    for (int i = 0; i < 16; i++) s += wsum[i];
    out[19267584] = s * (1.0f / 7225344.0f);
  }
}

// ---------- launch ----------
extern "C" void kernel_launch(void* const* d_in, const int* in_sizes, int n_in,
                              void* d_out, int out_size, void* d_ws, size_t ws_size,
                              hipStream_t stream)
{
  const float* x     = (const float*)d_in[0];
  const int*   shuf  = (const int*)d_in[1];
  const float* W_pe  = (const float*)d_in[2];
  const float* b_pe  = (const float*)d_in[3];
  const float* pos   = (const float*)d_in[4];
  const float* encW  = (const float*)d_in[5];
  const float* encB  = (const float*)d_in[6];
  const float* inW   = (const float*)d_in[7];
  const float* inB   = (const float*)d_in[8];
  const float* outW  = (const float*)d_in[9];
  const float* outB  = (const float*)d_in[10];
  const float* headW = (const float*)d_in[11];
  const float* headB = (const float*)d_in[12];
  const float* noise = (const float*)d_in[13];
  float* out = (float*)d_out;

  char* ws = (char*)d_ws;
  size_t cur = 0;
  auto alloc = [&](size_t bytes){ size_t o = cur; cur += (bytes + 255) & ~(size_t)255; return o; };

  int*   slot    = (int*)(ws + alloc(64*196*4));
  int*   tokcat  = (int*)(ws + alloc(14336*4));
  float* partial = (float*)(ws + alloc(9408*4));
  unsigned short* wcat    = (unsigned short*)(ws + alloc((size_t)1441792*2));
  unsigned short* encw_b  = wcat;
  unsigned short* inw_b   = wcat +  262144;   // [Wq;Wk;Wv]
  unsigned short* headw_b = wcat + 1048576;   // [768][512]
  unsigned short* WpeT  = (unsigned short*)(ws + alloc((size_t)393216*2));  // [768][512]
  unsigned short* outwT = (unsigned short*)(ws + alloc((size_t)262144*2));  // [512][512]
  unsigned short* Wqpe  = (unsigned short*)(ws + alloc((size_t)393216*2));  // [512][768]
  unsigned short* Wepe  = (unsigned short*)(ws + alloc((size_t)393216*2));  // [512][768]
  unsigned short* Whp   = (unsigned short*)(ws + alloc((size_t)393216*2));  // [768][512]
  unsigned short* pe2b  = (unsigned short*)(ws + alloc((size_t)131072*2));  // [256][512]
  float* peq  = (float*)(ws + alloc((size_t)131072*4));
  float* pee  = (float*)(ws + alloc((size_t)131072*4));
  float* bh32 = (float*)(ws + alloc(768*4));
  char* R0 = ws + alloc(26214400);
  unsigned short* maskA   = (unsigned short*)R0;
  unsigned short* unmaskA = (unsigned short*)(R0 + 15728640);
  unsigned short* attnout = (unsigned short*)R0;                 // alive attn..pred (maskA dead)
  unsigned short* predb   = (unsigned short*)(R0 + 10485760);    // alive pred..finalize
  unsigned short* enc   = (unsigned short*)(ws + alloc((size_t)2097152*2));
  unsigned short* qb    = (unsigned short*)(ws + alloc((size_t)5242880*2));
  unsigned short* kvb   = (unsigned short*)(ws + alloc((size_t)4194304*2));

  const int BIG = 0x7FFFFFFF;

  prep_all<<<21061, 256, 0, stream>>>(shuf, slot, W_pe, outW, WpeT, outwT,
                                      encW, inW, headW, wcat,
                                      pos, b_pe, outB, headB, pe2b, bh32,
                                      x, maskA, unmaskA, tokcat);

  // fold GEMMs (one launch, 176 blocks)
  {
    GD t1 = { inw_b,  WpeT,   nullptr, nullptr, Wqpe,   nullptr, 768, 512, 4,   0, 12 };
    GD t2 = { encw_b, WpeT,   nullptr, nullptr, Wepe,   nullptr, 768, 512, 4,  48, 12 };
    GD t3 = { headw_b,outwT,  nullptr, nullptr, Whp,    nullptr, 512, 512, 4,  96,  8 };
    GD t4 = { pe2b,   inw_b,  inB,     nullptr, nullptr, peq,    512, 512, 3, 144,  8 };
    GD t5 = { pe2b,   encw_b, encB,    nullptr, nullptr, pee,    512, 512, 3, 160,  8 };
    gemm2<<<176, 256, 0, stream>>>(t1, t2, t3, t4, t5);
  }
  // q + enc (one launch, 896 blocks)
  {
    GD q  = { maskA,   Wqpe, peq, tokcat,         qb,  nullptr, 512, 768, 1,   0, 8 };
    GD en = { unmaskA, Wepe, pee, tokcat + 10240, enc, nullptr, 512, 768, 2, 640, 8 };
    GD nz = q; nz.blk0 = BIG;
    gemm2<<<896, 256, 0, stream>>>(q, en, nz, nz, nz);
  }
  // kv = enc @ [Wk;Wv]^T + [bk;bv]
  {
    GD kv = { enc, inw_b + (size_t)512*512, inB + 512, nullptr, kvb, nullptr, 1024, 512, 0, 0, 16 };
    GD nz = kv; nz.blk0 = BIG;
    gemm2<<<512, 256, 0, stream>>>(kv, nz, nz, nz, nz);
  }
  attn_mfma<<<512, 256, 0, stream>>>(qb, kvb, attnout);
  // pred = attn_raw @ Whp^T + bh
  {
    GD pr = { attnout, Whp, bh32, nullptr, predb, nullptr, 768, 512, 0, 0, 12 };
    GD nz = pr; nz.blk0 = BIG;
    gemm2<<<960, 256, 0, stream>>>(pr, nz, nz, nz, nz);
  }

  finalize_k<<<9408, 256, 0, stream>>>(x, slot, predb, noise, out, partial);
  mse_reduce<<<1, 1024, 0, stream>>>(partial, out);
}